// Round 4
// baseline (360.396 us; speedup 1.0000x reference)
//
#include <hip/hip_runtime.h>
#include <hip/hip_bf16.h>

// Problem constants
#define B_  4
#define S_  2048
#define D_  256
#define H_  8
#define HD_ 32
#define K_  204          // int(2048 * 0.1)
#define SCALE_ 0.17677669529663687f  // 1/sqrt(32)

// ---- workspace layout (float offsets) ----
#define OFF_IMP    0          // 8192 floats
#define OFF_KG     8192       // 208896 floats [B,H,K,hd]
#define OFF_VG     217088     // 208896 floats
#define OFF_META   425984     // 8 ints: [0]=bar_cnt [1]=bar_gen [2..5]=ticket cnt per batch
#define OFF_KIDX   434176     // 1024 ints
#define OFF_Q      435200     // 2097152 floats [B*S, D]
#define OFF_AO     2532352    // 2097152 floats [B*S, D]

#define GSTR 80    // gemm LDS row stride (shorts)
#define PSTR 228   // attn P row stride (bf16 elems)
#define VSTR 228   // attn V^T row stride

typedef __attribute__((ext_vector_type(8))) short short8v;
typedef __attribute__((ext_vector_type(4))) float f32x4;

static __device__ __forceinline__ unsigned short f2bf(float f) {
    unsigned int u = __float_as_uint(f);
    u += 0x7FFFu + ((u >> 16) & 1u);      // round-to-nearest-even
    return (unsigned short)(u >> 16);
}
static __device__ __forceinline__ float bf2f(unsigned short h) {
    return __uint_as_float((unsigned int)h << 16);
}
static __device__ __forceinline__ short8v pack_bf8(float4 a, float4 b) {
    short8v r;
    r[0]=(short)f2bf(a.x); r[1]=(short)f2bf(a.y); r[2]=(short)f2bf(a.z); r[3]=(short)f2bf(a.w);
    r[4]=(short)f2bf(b.x); r[5]=(short)f2bf(b.y); r[6]=(short)f2bf(b.z); r[7]=(short)f2bf(b.w);
    return r;
}
static __device__ __forceinline__ short8v ld_bf8(const unsigned short* p) {
    union { unsigned int u[4]; short8v v; } cv;
    const uint2 a  = *(const uint2*)(p);
    const uint2 b2 = *(const uint2*)(p + 4);
    cv.u[0] = a.x; cv.u[1] = a.y; cv.u[2] = b2.x; cv.u[3] = b2.y;
    return cv.v;
}
// 16 fp32 -> bf16 hi/lo planes (split precision), two 16B LDS stores each
static __device__ __forceinline__ void cvt_store16(
    unsigned short* hi, unsigned short* lo, const float4* v)
{
    #pragma unroll
    for (int q = 0; q < 2; ++q) {
        short8v h, l;
        #pragma unroll
        for (int e = 0; e < 2; ++e) {
            const float4 f = v[q*2 + e];
            const unsigned short h0 = f2bf(f.x), h1 = f2bf(f.y),
                                 h2 = f2bf(f.z), h3 = f2bf(f.w);
            h[e*4+0]=(short)h0; h[e*4+1]=(short)h1; h[e*4+2]=(short)h2; h[e*4+3]=(short)h3;
            l[e*4+0]=(short)f2bf(f.x - bf2f(h0));
            l[e*4+1]=(short)f2bf(f.y - bf2f(h1));
            l[e*4+2]=(short)f2bf(f.z - bf2f(h2));
            l[e*4+3]=(short)f2bf(f.w - bf2f(h3));
        }
        *(short8v*)(hi + q*8) = h;
        *(short8v*)(lo + q*8) = l;
    }
}

// ---- shared-memory union over all phases (max = gemm: 40960 B) ----
struct SharedU {
    union {
        struct { float xs[8 * D_]; float hred[8 * 64]; } g;                  // gate
        struct { float vs[S_]; } r;                                          // rank
        struct { float xs[4 * D_]; int toks[4]; } k;                         // kv
        struct { unsigned short Ash[64*GSTR]; unsigned short Asl[64*GSTR];
                 unsigned short Bsh[64*GSTR]; unsigned short Bsl[64*GSTR]; } m;  // gemm
        struct { unsigned short Pl[32*PSTR]; unsigned short VTl[32*VSTR];
                 float redl[4*32]; float invl[32]; } a;                      // attn
    };
};

// ---- device-scope grid barrier (512 blocks co-resident: launch_bounds(256,2)
//      caps VGPR<=256 -> >=2 blocks/CU capacity -> work-conserving dispatch
//      places all 512; generation counter re-zeroed by init kernel each iter) ----
static __device__ __forceinline__ void grid_barrier(int* meta, int target)
{
    __syncthreads();
    if (threadIdx.x == 0) {
        __threadfence();
        if (atomicAdd(&meta[0], 1) == (int)gridDim.x - 1) {
            atomicExch(&meta[0], 0);
            __threadfence();
            atomicAdd(&meta[1], 1);
        } else {
            while (atomicAdd(&meta[1], 0) < target) __builtin_amdgcn_s_sleep(2);
        }
        __threadfence();
    }
    __syncthreads();
}

// ---------------- phase A1: gate MLP -> importance logit ----------------
static __device__ __forceinline__ void gate_tile(
    SharedU& sh, const float* __restrict__ x, const float* __restrict__ gw1,
    const float* __restrict__ gb1, const float* __restrict__ gw2, float* ws, int vt)
{
    const int t0 = vt * 8;
    const int tid = threadIdx.x;
    float* xs = sh.g.xs;
    float* hred = sh.g.hred;
    __syncthreads();

    const float4* src = (const float4*)(x + (size_t)t0 * D_);
    ((float4*)xs)[tid]       = src[tid];
    ((float4*)xs)[tid + 256] = src[tid + 256];
    __syncthreads();

    const int c = tid & 3, f = tid >> 2;
    float4 wv[16];
    const float4* wr = (const float4*)(gw1 + (size_t)f * D_) + c;
    #pragma unroll
    for (int j = 0; j < 16; ++j) wv[j] = wr[j * 4];
    const float bb = gb1[f], g2 = gw2[f];

    #pragma unroll
    for (int tk = 0; tk < 8; ++tk) {
        const float4* xr = (const float4*)(xs + tk * D_) + c;
        float a = 0.0f;
        #pragma unroll
        for (int j = 0; j < 16; ++j) {
            float4 xv = xr[j * 4];
            a += wv[j].x*xv.x + wv[j].y*xv.y + wv[j].z*xv.z + wv[j].w*xv.w;
        }
        a += __shfl_xor(a, 1);
        a += __shfl_xor(a, 2);
        if (c == 0) hred[tk * 64 + f] = fmaxf(a + bb, 0.0f) * g2;
    }
    __syncthreads();

    const int tk = tid >> 5, ln = tid & 31;
    float s = hred[tk * 64 + ln] + hred[tk * 64 + ln + 32];
    #pragma unroll
    for (int o = 16; o; o >>= 1) s += __shfl_xor(s, o, 32);
    if (ln == 0) ws[OFF_IMP + t0 + tk] = s;
}

// ---------------- phase B: exact rank -> ticketed compact index (unsorted) ----------------
// kept set identical to lax.top_k (rank = #greater + #equal-with-smaller-index < K).
// Slot order within kidx is nondeterministic; attention is key-order invariant.
static __device__ __forceinline__ void rank_tile(
    SharedU& sh, const float* __restrict__ imp, int* kidx, int* meta, int vt)
{
    const int b  = vt >> 7;
    const int ic = vt & 127;
    const int tid = threadIdx.x;
    float* vs = sh.r.vs;
    __syncthreads();
    const float* src = imp + b * S_;
    #pragma unroll
    for (int cc = 0; cc < 2; ++cc)
        ((float4*)vs)[tid + cc*256] = ((const float4*)src)[tid + cc*256];
    __syncthreads();

    const int il = tid >> 4;
    const int c  = tid & 15;
    const int i  = ic * 16 + il;
    const float vi = vs[i];
    int gt = 0, eq = 0;
    const float4* v4 = (const float4*)vs + c * 32;
    #pragma unroll 8
    for (int t = 0; t < 32; ++t) {
        const int j4 = (t + c) & 31;
        float4 w = v4[j4];
        const int base = c * 128 + j4 * 4;
        gt += (w.x > vi); eq += (w.x == vi) && (base + 0 < i);
        gt += (w.y > vi); eq += (w.y == vi) && (base + 1 < i);
        gt += (w.z > vi); eq += (w.z == vi) && (base + 2 < i);
        gt += (w.w > vi); eq += (w.w == vi) && (base + 3 < i);
    }
    int r = gt + eq;
    r += __shfl_xor(r, 1);
    r += __shfl_xor(r, 2);
    r += __shfl_xor(r, 4);
    r += __shfl_xor(r, 8);
    if (c == 0 && r < K_) {
        const int p = atomicAdd(&meta[2 + b], 1);
        kidx[b * K_ + p] = i;
    }
    __syncthreads();
}

// ---------------- phase C: K/V projection for kept keys ----------------
static __device__ __forceinline__ void kv_tile(
    SharedU& sh, const float* __restrict__ x, const float* __restrict__ w_in,
    const float* __restrict__ b_in, float* ws, const int* __restrict__ kidx, int vt)
{
    const int b = vt / 51, j0 = (vt % 51) * 4, tid = threadIdx.x;
    float* xs = sh.k.xs;
    int* toks = sh.k.toks;
    __syncthreads();
    if (tid < 4) {
        int tk = kidx[b * K_ + j0 + tid];
        toks[tid] = min(max(tk, 0), S_ - 1);
    }
    __syncthreads();
    {
        const int kk = tid >> 6, l = tid & 63;
        ((float4*)xs)[kk * 64 + l] =
            ((const float4*)(x + ((size_t)b * S_ + toks[kk]) * D_))[l];
    }
    __syncthreads();

    const int c = tid & 3, f = tid >> 2;
    #pragma unroll 1
    for (int fg = 0; fg < 8; ++fg) {
        const int eh = fg * 64 + f;
        float4 wv[16];
        const float4* wr = (const float4*)(w_in + (size_t)(D_ + eh) * D_) + c;
        #pragma unroll
        for (int j = 0; j < 16; ++j) wv[j] = wr[j * 4];
        float a0 = 0, a1 = 0, a2 = 0, a3 = 0;
        #pragma unroll
        for (int j = 0; j < 16; ++j) {
            float4 w = wv[j];
            float4 x0 = ((const float4*)(xs + 0*D_))[c + j*4];
            float4 x1 = ((const float4*)(xs + 1*D_))[c + j*4];
            float4 x2 = ((const float4*)(xs + 2*D_))[c + j*4];
            float4 x3 = ((const float4*)(xs + 3*D_))[c + j*4];
            a0 += w.x*x0.x + w.y*x0.y + w.z*x0.z + w.w*x0.w;
            a1 += w.x*x1.x + w.y*x1.y + w.z*x1.z + w.w*x1.w;
            a2 += w.x*x2.x + w.y*x2.y + w.z*x2.z + w.w*x2.w;
            a3 += w.x*x3.x + w.y*x3.y + w.z*x3.z + w.w*x3.w;
        }
        a0 += __shfl_xor(a0, 1); a0 += __shfl_xor(a0, 2);
        a1 += __shfl_xor(a1, 1); a1 += __shfl_xor(a1, 2);
        a2 += __shfl_xor(a2, 1); a2 += __shfl_xor(a2, 2);
        a3 += __shfl_xor(a3, 1); a3 += __shfl_xor(a3, 2);
        if (c == 0) {
            const float bias = b_in[D_ + eh];
            const int isV = eh >> 8;
            const int ee = eh & 255;
            const int h = ee >> 5, d = ee & 31;
            float* dst = ws + (isV ? OFF_VG : OFF_KG) + ((b * H_ + h) * K_) * HD_ + d;
            dst[(j0 + 0) * HD_] = a0 + bias;
            dst[(j0 + 1) * HD_] = a1 + bias;
            dst[(j0 + 2) * HD_] = a2 + bias;
            dst[(j0 + 3) * HD_] = a3 + bias;
        }
    }
    __syncthreads();
}

// ---------------- phases A2/E: MFMA split-bf16 GEMM tile ----------------
// C[M,256] = A[M,256] * W[256,256]^T + bias; A=Ah+Al, W=Wh+Wl (bf16),
// C ~= Ah*Wh + Ah*Wl + Al*Wh, fp32 accum. vt: mtile = vt&127, ntile = vt>>7.
static __device__ __forceinline__ void gemm_tile(
    SharedU& sh, const float* __restrict__ A, const float* __restrict__ W,
    const float* __restrict__ bias, float* __restrict__ C, int vt)
{
    const int tid = threadIdx.x;
    const int m0 = (vt & 127) * 64, n0 = (vt >> 7) * 64;
    const int lane = tid & 63, w = tid >> 6;
    const int c = lane & 15, g = lane >> 4;
    const int mq = w >> 1, nq = w & 1;

    const f32x4 zf = {0.0f, 0.0f, 0.0f, 0.0f};
    f32x4 acc[2][2] = {{zf, zf}, {zf, zf}};

    const int srow = tid >> 2, sseg = tid & 3;
    const float* Ap = A + (size_t)(m0 + srow) * D_ + sseg * 16;
    const float* Wp = W + (size_t)(n0 + srow) * D_ + sseg * 16;

    float4 ar[4], br[4];
    #pragma unroll
    for (int j = 0; j < 4; ++j) { ar[j] = ((const float4*)Ap)[j]; br[j] = ((const float4*)Wp)[j]; }

    for (int k0 = 0; k0 < D_; k0 += 64) {
        __syncthreads();
        cvt_store16(&sh.m.Ash[srow*GSTR + sseg*16], &sh.m.Asl[srow*GSTR + sseg*16], ar);
        cvt_store16(&sh.m.Bsh[srow*GSTR + sseg*16], &sh.m.Bsl[srow*GSTR + sseg*16], br);
        __syncthreads();
        if (k0 + 64 < D_) {
            #pragma unroll
            for (int j = 0; j < 4; ++j) {
                ar[j] = ((const float4*)(Ap + k0 + 64))[j];
                br[j] = ((const float4*)(Wp + k0 + 64))[j];
            }
        }
        #pragma unroll
        for (int ks = 0; ks < 2; ++ks) {
            short8v am[2][2], bm[2][2];
            #pragma unroll
            for (int t = 0; t < 2; ++t) {
                const int ra = (mq*32 + t*16 + c) * GSTR + ks*32 + g*8;
                am[t][0] = *(const short8v*)&sh.m.Ash[ra];
                am[t][1] = *(const short8v*)&sh.m.Asl[ra];
                const int rb = (nq*32 + t*16 + c) * GSTR + ks*32 + g*8;
                bm[t][0] = *(const short8v*)&sh.m.Bsh[rb];
                bm[t][1] = *(const short8v*)&sh.m.Bsl[rb];
            }
            #pragma unroll
            for (int mt = 0; mt < 2; ++mt)
                #pragma unroll
                for (int nt = 0; nt < 2; ++nt) {
                    acc[mt][nt] = __builtin_amdgcn_mfma_f32_16x16x32_bf16(am[mt][0], bm[nt][0], acc[mt][nt], 0, 0, 0);
                    acc[mt][nt] = __builtin_amdgcn_mfma_f32_16x16x32_bf16(am[mt][0], bm[nt][1], acc[mt][nt], 0, 0, 0);
                    acc[mt][nt] = __builtin_amdgcn_mfma_f32_16x16x32_bf16(am[mt][1], bm[nt][0], acc[mt][nt], 0, 0, 0);
                }
        }
    }
    #pragma unroll
    for (int nt = 0; nt < 2; ++nt) {
        const int n = n0 + nq*32 + nt*16 + c;
        const float bv = bias[n];
        #pragma unroll
        for (int mt = 0; mt < 2; ++mt) {
            const int m = m0 + mq*32 + mt*16 + g*4;
            #pragma unroll
            for (int r = 0; r < 4; ++r)
                C[(size_t)(m + r) * D_ + n] = acc[mt][nt][r] + bv;
        }
    }
    __syncthreads();
}

// ---------------- phase D: attention core (MFMA bf16, fp32 accum) ----------------
static __device__ __forceinline__ void attn_tile(
    SharedU& sh, const float* __restrict__ ws, float* __restrict__ ao, int vt)
{
    const int b = vt >> 9, h = (vt >> 6) & 7, q0 = (vt & 63) * 32;
    const int tid = threadIdx.x;
    const int lane = tid & 63, w = tid >> 6;
    const int c = lane & 15, g = lane >> 4;

    unsigned short* Pl  = sh.a.Pl;
    unsigned short* VTl = sh.a.VTl;
    float* redl = sh.a.redl;
    float* invl = sh.a.invl;

    __syncthreads();   // protect LDS reuse across tiles/phases

    const float* KGb = ws + OFF_KG + (size_t)(b * H_ + h) * K_ * HD_;
    const float* VGb = ws + OFF_VG + (size_t)(b * H_ + h) * K_ * HD_;

    for (int i = tid; i < K_ * 8; i += 256) {
        const int j = i >> 3, dc = i & 7;
        const float4 v = ((const float4*)VGb)[i];
        VTl[(dc*4+0)*VSTR + j] = f2bf(v.x);
        VTl[(dc*4+1)*VSTR + j] = f2bf(v.y);
        VTl[(dc*4+2)*VSTR + j] = f2bf(v.z);
        VTl[(dc*4+3)*VSTR + j] = f2bf(v.w);
    }
    {   // P pad: j = 208..223 for all 32 q rows
        const int q = tid >> 3, cc = tid & 7;
        *(unsigned int*)&Pl[q * PSTR + 208 + cc * 2] = 0u;
    }
    for (int i = tid; i < 32 * 20; i += 256) {   // VT pad: j = 204..223
        VTl[(i / 20) * VSTR + 204 + (i % 20)] = 0;
    }

    short8v qa[2];
    #pragma unroll
    for (int qt = 0; qt < 2; ++qt) {
        const float* qp = ws + OFF_Q + (size_t)(b * S_ + q0 + qt*16 + c) * D_ + h * HD_ + g * 8;
        qa[qt] = pack_bf8(*(const float4*)qp, *(const float4*)(qp + 4));
    }
    const int njt = (w == 0) ? 4 : 3;
    f32x4 acc[2][4];
    const f32x4 zf = {0.0f, 0.0f, 0.0f, 0.0f};
    #pragma unroll
    for (int qt = 0; qt < 2; ++qt)
        #pragma unroll
        for (int t = 0; t < 4; ++t) acc[qt][t] = zf;

    for (int t = 0; t < njt; ++t) {
        const int jt = w + 4 * t;
        const int jc = min(jt * 16 + c, K_ - 1);
        const float* kp = KGb + (size_t)jc * HD_ + g * 8;
        const short8v kb = pack_bf8(*(const float4*)kp, *(const float4*)(kp + 4));
        acc[0][t] = __builtin_amdgcn_mfma_f32_16x16x32_bf16(qa[0], kb, acc[0][t], 0, 0, 0);
        acc[1][t] = __builtin_amdgcn_mfma_f32_16x16x32_bf16(qa[1], kb, acc[1][t], 0, 0, 0);
    }

    float rs[2][4] = {{0,0,0,0},{0,0,0,0}};
    for (int t = 0; t < njt; ++t) {
        const int jg = (w + 4 * t) * 16 + c;
        const bool val = (jg < K_);
        #pragma unroll
        for (int qt = 0; qt < 2; ++qt) {
            #pragma unroll
            for (int r = 0; r < 4; ++r) {
                const float e = val ? __expf(acc[qt][t][r] * SCALE_) : 0.0f;
                rs[qt][r] += e;
                Pl[(qt*16 + g*4 + r) * PSTR + jg] = f2bf(e);
            }
        }
    }
    #pragma unroll
    for (int qt = 0; qt < 2; ++qt)
        #pragma unroll
        for (int r = 0; r < 4; ++r) {
            float s = rs[qt][r];
            s += __shfl_xor(s, 1); s += __shfl_xor(s, 2);
            s += __shfl_xor(s, 4); s += __shfl_xor(s, 8);
            if (c == 0) redl[w * 32 + qt*16 + g*4 + r] = s;
        }

    __syncthreads();
    if (tid < 32)
        invl[tid] = 1.0f / (redl[tid] + redl[32 + tid] + redl[64 + tid] + redl[96 + tid]);
    __syncthreads();

    const int dt = w >> 1, qt2 = w & 1;
    f32x4 o = zf;
    const unsigned short* vb = &VTl[(dt*16 + c) * VSTR];
    const unsigned short* pb = &Pl[(qt2*16 + c) * PSTR];
    #pragma unroll
    for (int kt = 0; kt < 7; ++kt) {
        const short8v av = ld_bf8(vb + kt*32 + g*8);
        const short8v bv = ld_bf8(pb + kt*32 + g*8);
        o = __builtin_amdgcn_mfma_f32_16x16x32_bf16(av, bv, o, 0, 0, 0);
    }
    const float iv = invl[qt2*16 + c];
    float4 r4; r4.x = o[0]*iv; r4.y = o[1]*iv; r4.z = o[2]*iv; r4.w = o[3]*iv;
    *(float4*)(ao + (size_t)(b * S_ + q0 + qt2*16 + c) * D_ + h * HD_ + dt*16 + g*4) = r4;
    __syncthreads();
}

// ---------------- init: zero barrier/ticket state (workspace is poisoned) ----------------
__global__ void init_kernel(int* meta)
{
    if (threadIdx.x < 8) meta[threadIdx.x] = 0;
}

// ---------------- mega kernel: all phases, grid barriers between ----------------
__global__ __launch_bounds__(256, 2) void mega_kernel(
    const float* __restrict__ x, const float* __restrict__ w_in,
    const float* __restrict__ b_in, const float* __restrict__ w_out,
    const float* __restrict__ b_out, const float* __restrict__ gw1,
    const float* __restrict__ gb1, const float* __restrict__ gw2,
    float* __restrict__ ws, float* __restrict__ out)
{
    __shared__ __align__(16) SharedU sh;
    int* meta = (int*)(ws + OFF_META);
    int* kidx = (int*)(ws + OFF_KIDX);
    const int bid = blockIdx.x, nb = gridDim.x;

    // phase A: gate (1024 tiles) + Q projection GEMM (512 tiles) — independent
    for (int vt = bid; vt < 1024; vt += nb) gate_tile(sh, x, gw1, gb1, gw2, ws, vt);
    for (int vt = bid; vt < 512; vt += nb) gemm_tile(sh, x, w_in, b_in, ws + OFF_Q, vt);
    grid_barrier(meta, 1);

    // phase B: rank + ticketed emit (512 tiles)
    for (int vt = bid; vt < 512; vt += nb) rank_tile(sh, ws + OFF_IMP, kidx, meta, vt);
    grid_barrier(meta, 2);

    // phase C: K/V projection for kept keys (204 tiles)
    for (int vt = bid; vt < 204; vt += nb) kv_tile(sh, x, w_in, b_in, ws, kidx, vt);
    grid_barrier(meta, 3);

    // phase D: attention (2048 tiles)
    for (int vt = bid; vt < 2048; vt += nb) attn_tile(sh, ws, ws + OFF_AO, vt);
    grid_barrier(meta, 4);

    // phase E: out projection GEMM (512 tiles)
    for (int vt = bid; vt < 512; vt += nb) gemm_tile(sh, ws + OFF_AO, w_out, b_out, out, vt);
}

extern "C" void kernel_launch(void* const* d_in, const int* in_sizes, int n_in,
                              void* d_out, int out_size, void* d_ws, size_t ws_size,
                              hipStream_t stream)
{
    const float* x     = (const float*)d_in[0];
    const float* w_in  = (const float*)d_in[1];
    const float* b_in  = (const float*)d_in[2];
    const float* w_out = (const float*)d_in[3];
    const float* b_out = (const float*)d_in[4];
    const float* gw1   = (const float*)d_in[5];
    const float* gb1   = (const float*)d_in[6];
    const float* gw2   = (const float*)d_in[7];
    // d_in[8] = gate_b2: constant inside monotone sigmoid -> doesn't affect top-k

    float* ws = (float*)d_ws;
    int* meta = (int*)(ws + OFF_META);
    float* out = (float*)d_out;

    init_kernel<<<1, 64, 0, stream>>>(meta);
    mega_kernel<<<512, 256, 0, stream>>>(x, w_in, b_in, w_out, b_out,
                                         gw1, gb1, gw2, ws, out);
}

// Round 5
// 163.639 us; speedup vs baseline: 2.2024x; 2.2024x over previous
//
#include <hip/hip_runtime.h>
#include <hip/hip_bf16.h>

// Problem constants
#define B_  4
#define S_  2048
#define D_  256
#define H_  8
#define HD_ 32
#define K_  204          // int(2048 * 0.1)
#define SCALE_ 0.17677669529663687f  // 1/sqrt(32)

// ---- workspace layout (float offsets) ----
// bf16 arrays stored as unsigned short; float-slot counts = shorts/2
#define OFF_IMP    0          // 8192 floats
#define OFF_KG     8192       // 208896 shorts (104448 slots) [B,H,K,hd] bf16
#define OFF_VG     112640     // 208896 shorts
#define OFF_META   217088     // 8 ints (ticket counters)
#define OFF_KIDX   217104     // 1024 ints
#define OFF_Q      218368     // 2097152 shorts [B*S, D] bf16
#define OFF_XH     1266944    // 2097152 shorts: x hi plane
#define OFF_XL     2315520    // 2097152 shorts: x lo plane
#define OFF_AOH    3364096    // 2097152 shorts: attn-out hi plane
#define OFF_AOL    4412672    // 2097152 shorts: attn-out lo plane
#define OFF_WQH    5461248    // 65536 shorts: w_in[0:256] hi
#define OFF_WQL    5494016    // 65536 shorts: w_in[0:256] lo
#define OFF_WOH    5526784    // 65536 shorts: w_out hi
#define OFF_WOL    5559552    // 65536 shorts: w_out lo
// total ~22.4 MB

#define GSTR 80    // gemm LDS row stride (shorts)
#define PSTR 228   // attn P row stride (bf16 elems)
#define VSTR 228   // attn V^T row stride

typedef __attribute__((ext_vector_type(8))) short short8v;
typedef __attribute__((ext_vector_type(4))) float f32x4;
typedef unsigned short ushort_t;

static __device__ __forceinline__ unsigned short f2bf(float f) {
    unsigned int u = __float_as_uint(f);
    u += 0x7FFFu + ((u >> 16) & 1u);      // round-to-nearest-even
    return (unsigned short)(u >> 16);
}
static __device__ __forceinline__ float bf2f(unsigned short h) {
    return __uint_as_float((unsigned int)h << 16);
}
static __device__ __forceinline__ short8v ld_bf8(const unsigned short* p) {
    union { unsigned int u[4]; short8v v; } cv;
    const uint2 a  = *(const uint2*)(p);
    const uint2 b2 = *(const uint2*)(p + 4);
    cv.u[0] = a.x; cv.u[1] = a.y; cv.u[2] = b2.x; cv.u[3] = b2.y;
    return cv.v;
}
// split 8 contiguous fp32 -> bf16 hi/lo planes (16B store each)
static __device__ __forceinline__ void split_store8(
    const float* __restrict__ src, unsigned short* dh, unsigned short* dl)
{
    short8v h, l;
    #pragma unroll
    for (int e = 0; e < 8; ++e) {
        const float f = src[e];
        const unsigned short hh = f2bf(f);
        h[e] = (short)hh;
        l[e] = (short)f2bf(f - bf2f(hh));
    }
    *(short8v*)dh = h;
    *(short8v*)dl = l;
}

// ---------------- kernel 1: gate MLP + x/weight plane conversion ----------------
__global__ __launch_bounds__(256) void gate_kernel(
    const float* __restrict__ x, const float* __restrict__ gw1,
    const float* __restrict__ gb1, const float* __restrict__ gw2,
    const float* __restrict__ w_in, const float* __restrict__ w_out, float* ws)
{
    const int t0 = blockIdx.x * 8;
    const int tid = threadIdx.x;
    __shared__ __align__(16) float xs[8 * D_];
    __shared__ float hred[8 * 64];

    const float4* src = (const float4*)(x + (size_t)t0 * D_);
    ((float4*)xs)[tid]       = src[tid];
    ((float4*)xs)[tid + 256] = src[tid + 256];
    __syncthreads();

    // emit x bf16 hi/lo planes from the staged tile (no extra global reads)
    {
        unsigned short* XH = (unsigned short*)(ws + OFF_XH);
        unsigned short* XL = (unsigned short*)(ws + OFF_XL);
        split_store8(xs + tid * 8, XH + (size_t)t0 * D_ + tid * 8,
                                   XL + (size_t)t0 * D_ + tid * 8);
    }
    // blocks 0..63: convert weights (w_in rows 0..255, then w_out) to planes
    if (blockIdx.x < 64) {
        const int e0 = blockIdx.x * 2048 + tid * 8;
        if (e0 < 65536) {
            split_store8(w_in + e0, (unsigned short*)(ws + OFF_WQH) + e0,
                                    (unsigned short*)(ws + OFF_WQL) + e0);
        } else {
            const int e = e0 - 65536;
            split_store8(w_out + e, (unsigned short*)(ws + OFF_WOH) + e,
                                    (unsigned short*)(ws + OFF_WOL) + e);
        }
    }
    if (blockIdx.x == 0 && tid < 8) ((int*)(ws + OFF_META))[tid] = 0;

    const int c = tid & 3, f = tid >> 2;
    float4 wv[16];
    const float4* wr = (const float4*)(gw1 + (size_t)f * D_) + c;
    #pragma unroll
    for (int j = 0; j < 16; ++j) wv[j] = wr[j * 4];
    const float bb = gb1[f], g2 = gw2[f];

    #pragma unroll
    for (int tk = 0; tk < 8; ++tk) {
        const float4* xr = (const float4*)(xs + tk * D_) + c;
        float a = 0.0f;
        #pragma unroll
        for (int j = 0; j < 16; ++j) {
            float4 xv = xr[j * 4];
            a += wv[j].x*xv.x + wv[j].y*xv.y + wv[j].z*xv.z + wv[j].w*xv.w;
        }
        a += __shfl_xor(a, 1);
        a += __shfl_xor(a, 2);
        if (c == 0) hred[tk * 64 + f] = fmaxf(a + bb, 0.0f) * g2;
    }
    __syncthreads();

    const int tk = tid >> 5, ln = tid & 31;
    float s = hred[tk * 64 + ln] + hred[tk * 64 + ln + 32];
    #pragma unroll
    for (int o = 16; o; o >>= 1) s += __shfl_xor(s, o, 32);
    if (ln == 0) ws[OFF_IMP + t0 + tk] = s;
}

// ---------------- kernel 2: exact rank -> ticketed compact index (unsorted) ----------------
// kept set identical to lax.top_k (rank = #greater + #equal-with-smaller-index < K).
// Slot order nondeterministic; attention is key-order invariant (validated r4).
__global__ __launch_bounds__(256) void rank_kernel(
    const float* __restrict__ ws_imp, int* kidx, int* meta)
{
    const int b  = blockIdx.x >> 7;
    const int ic = blockIdx.x & 127;
    const int tid = threadIdx.x;
    __shared__ __align__(16) float vs[S_];
    const float* src = ws_imp + b * S_;
    #pragma unroll
    for (int cc = 0; cc < 2; ++cc)
        ((float4*)vs)[tid + cc*256] = ((const float4*)src)[tid + cc*256];
    __syncthreads();

    const int il = tid >> 4;
    const int c  = tid & 15;
    const int i  = ic * 16 + il;
    const float vi = vs[i];
    int gt = 0, eq = 0;
    const float4* v4 = (const float4*)vs + c * 32;
    #pragma unroll 8
    for (int t = 0; t < 32; ++t) {
        const int j4 = (t + c) & 31;
        float4 w = v4[j4];
        const int base = c * 128 + j4 * 4;
        gt += (w.x > vi); eq += (w.x == vi) && (base + 0 < i);
        gt += (w.y > vi); eq += (w.y == vi) && (base + 1 < i);
        gt += (w.z > vi); eq += (w.z == vi) && (base + 2 < i);
        gt += (w.w > vi); eq += (w.w == vi) && (base + 3 < i);
    }
    int r = gt + eq;
    r += __shfl_xor(r, 1);
    r += __shfl_xor(r, 2);
    r += __shfl_xor(r, 4);
    r += __shfl_xor(r, 8);
    if (c == 0 && r < K_) {
        const int p = atomicAdd(&meta[2 + b], 1);
        kidx[b * K_ + p] = i;
    }
}

// ---------------- kernel 3: K/V projection for kept keys -> bf16 ----------------
__global__ __launch_bounds__(256) void kv_kernel(
    const float* __restrict__ x, const float* __restrict__ w_in,
    const float* __restrict__ b_in, unsigned short* __restrict__ KG,
    unsigned short* __restrict__ VG, const int* __restrict__ kidx)
{
    const int b = blockIdx.y, j0 = blockIdx.x * 4, tid = threadIdx.x;
    __shared__ __align__(16) float xs[4 * D_];
    __shared__ int toks[4];
    if (tid < 4) {
        int tk = kidx[b * K_ + j0 + tid];
        toks[tid] = min(max(tk, 0), S_ - 1);
    }
    __syncthreads();
    {
        const int kk = tid >> 6, l = tid & 63;
        ((float4*)xs)[kk * 64 + l] =
            ((const float4*)(x + ((size_t)b * S_ + toks[kk]) * D_))[l];
    }
    __syncthreads();

    const int c = tid & 3, f = tid >> 2;
    #pragma unroll 1
    for (int fg = 0; fg < 8; ++fg) {
        const int eh = fg * 64 + f;
        float4 wv[16];
        const float4* wr = (const float4*)(w_in + (size_t)(D_ + eh) * D_) + c;
        #pragma unroll
        for (int j = 0; j < 16; ++j) wv[j] = wr[j * 4];
        float a0 = 0, a1 = 0, a2 = 0, a3 = 0;
        #pragma unroll
        for (int j = 0; j < 16; ++j) {
            float4 w = wv[j];
            float4 x0 = ((const float4*)(xs + 0*D_))[c + j*4];
            float4 x1 = ((const float4*)(xs + 1*D_))[c + j*4];
            float4 x2 = ((const float4*)(xs + 2*D_))[c + j*4];
            float4 x3 = ((const float4*)(xs + 3*D_))[c + j*4];
            a0 += w.x*x0.x + w.y*x0.y + w.z*x0.z + w.w*x0.w;
            a1 += w.x*x1.x + w.y*x1.y + w.z*x1.z + w.w*x1.w;
            a2 += w.x*x2.x + w.y*x2.y + w.z*x2.z + w.w*x2.w;
            a3 += w.x*x3.x + w.y*x3.y + w.z*x3.z + w.w*x3.w;
        }
        a0 += __shfl_xor(a0, 1); a0 += __shfl_xor(a0, 2);
        a1 += __shfl_xor(a1, 1); a1 += __shfl_xor(a1, 2);
        a2 += __shfl_xor(a2, 1); a2 += __shfl_xor(a2, 2);
        a3 += __shfl_xor(a3, 1); a3 += __shfl_xor(a3, 2);
        if (c == 0) {
            const float bias = b_in[D_ + eh];
            const int isV = eh >> 8;
            const int ee = eh & 255;
            const int h = ee >> 5, d = ee & 31;
            unsigned short* dst = (isV ? VG : KG) + ((b * H_ + h) * K_) * HD_ + d;
            dst[(j0 + 0) * HD_] = f2bf(a0 + bias);
            dst[(j0 + 1) * HD_] = f2bf(a1 + bias);
            dst[(j0 + 2) * HD_] = f2bf(a2 + bias);
            dst[(j0 + 3) * HD_] = f2bf(a3 + bias);
        }
    }
}

// ---------------- kernel 4: MFMA split-bf16 GEMM (pre-converted planes) ----------------
// C = A * W^T + bias where A = Ah+Al, W = Wh+Wl (bf16 planes in global).
// C ~= Ah*Wh + Ah*Wl + Al*Wh, fp32 accum. Zero conversion VALU in-loop.
// QOUT: store bf16 (Q path); else fp32 (final out).
template<bool QOUT>
__global__ __launch_bounds__(256) void gemm_kernel(
    const unsigned short* __restrict__ Ah, const unsigned short* __restrict__ Al,
    const unsigned short* __restrict__ Bh, const unsigned short* __restrict__ Bl,
    const float* __restrict__ bias, float* __restrict__ Cf,
    unsigned short* __restrict__ Cq)
{
    __shared__ __align__(16) unsigned short Ash[64 * GSTR];
    __shared__ __align__(16) unsigned short Asl[64 * GSTR];
    __shared__ __align__(16) unsigned short Bsh[64 * GSTR];
    __shared__ __align__(16) unsigned short Bsl[64 * GSTR];

    const int tid = threadIdx.x;
    const int m0 = blockIdx.x * 64, n0 = blockIdx.y * 64;
    const int lane = tid & 63, w = tid >> 6;
    const int c = lane & 15, g = lane >> 4;
    const int mq = w >> 1, nq = w & 1;

    const f32x4 zf = {0.0f, 0.0f, 0.0f, 0.0f};
    f32x4 acc[2][2] = {{zf, zf}, {zf, zf}};

    const int srow = tid >> 2, sseg = tid & 3;
    const unsigned short* Aph = Ah + (size_t)(m0 + srow) * D_ + sseg * 16;
    const unsigned short* Apl = Al + (size_t)(m0 + srow) * D_ + sseg * 16;
    const unsigned short* Bph = Bh + (size_t)(n0 + srow) * D_ + sseg * 16;
    const unsigned short* Bpl = Bl + (size_t)(n0 + srow) * D_ + sseg * 16;

    short8v arh[2], arl[2], brh[2], brl[2];
    #pragma unroll
    for (int u = 0; u < 2; ++u) {
        arh[u] = *(const short8v*)(Aph + u*8); arl[u] = *(const short8v*)(Apl + u*8);
        brh[u] = *(const short8v*)(Bph + u*8); brl[u] = *(const short8v*)(Bpl + u*8);
    }

    for (int k0 = 0; k0 < D_; k0 += 64) {
        __syncthreads();
        #pragma unroll
        for (int u = 0; u < 2; ++u) {
            *(short8v*)&Ash[srow*GSTR + sseg*16 + u*8] = arh[u];
            *(short8v*)&Asl[srow*GSTR + sseg*16 + u*8] = arl[u];
            *(short8v*)&Bsh[srow*GSTR + sseg*16 + u*8] = brh[u];
            *(short8v*)&Bsl[srow*GSTR + sseg*16 + u*8] = brl[u];
        }
        __syncthreads();
        if (k0 + 64 < D_) {
            #pragma unroll
            for (int u = 0; u < 2; ++u) {
                arh[u] = *(const short8v*)(Aph + k0 + 64 + u*8);
                arl[u] = *(const short8v*)(Apl + k0 + 64 + u*8);
                brh[u] = *(const short8v*)(Bph + k0 + 64 + u*8);
                brl[u] = *(const short8v*)(Bpl + k0 + 64 + u*8);
            }
        }
        #pragma unroll
        for (int ks = 0; ks < 2; ++ks) {
            short8v am[2][2], bm[2][2];
            #pragma unroll
            for (int t = 0; t < 2; ++t) {
                const int ra = (mq*32 + t*16 + c) * GSTR + ks*32 + g*8;
                am[t][0] = *(const short8v*)&Ash[ra];
                am[t][1] = *(const short8v*)&Asl[ra];
                const int rb = (nq*32 + t*16 + c) * GSTR + ks*32 + g*8;
                bm[t][0] = *(const short8v*)&Bsh[rb];
                bm[t][1] = *(const short8v*)&Bsl[rb];
            }
            #pragma unroll
            for (int mt = 0; mt < 2; ++mt)
                #pragma unroll
                for (int nt = 0; nt < 2; ++nt) {
                    acc[mt][nt] = __builtin_amdgcn_mfma_f32_16x16x32_bf16(am[mt][0], bm[nt][0], acc[mt][nt], 0, 0, 0);
                    acc[mt][nt] = __builtin_amdgcn_mfma_f32_16x16x32_bf16(am[mt][0], bm[nt][1], acc[mt][nt], 0, 0, 0);
                    acc[mt][nt] = __builtin_amdgcn_mfma_f32_16x16x32_bf16(am[mt][1], bm[nt][0], acc[mt][nt], 0, 0, 0);
                }
        }
    }
    #pragma unroll
    for (int nt = 0; nt < 2; ++nt) {
        const int n = n0 + nq*32 + nt*16 + c;
        const float bv = bias[n];
        #pragma unroll
        for (int mt = 0; mt < 2; ++mt) {
            const int m = m0 + mq*32 + mt*16 + g*4;
            #pragma unroll
            for (int r = 0; r < 4; ++r) {
                const float v = acc[mt][nt][r] + bv;
                if (QOUT) Cq[(size_t)(m + r) * D_ + n] = f2bf(v);
                else      Cf[(size_t)(m + r) * D_ + n] = v;
            }
        }
    }
}

// ---------------- kernel 5: attention core (bf16 in, planes out) ----------------
__global__ __launch_bounds__(256) void attn_kernel(
    const unsigned short* __restrict__ KG, const unsigned short* __restrict__ VG,
    const unsigned short* __restrict__ Qb,
    unsigned short* __restrict__ aoh, unsigned short* __restrict__ aol)
{
    const int b = blockIdx.z, h = blockIdx.y, q0 = blockIdx.x * 32;
    const int tid = threadIdx.x;
    const int lane = tid & 63, w = tid >> 6;
    const int c = lane & 15, g = lane >> 4;

    __shared__ __align__(16) unsigned short Pl[32 * PSTR];    // P[q][j] bf16
    __shared__ __align__(16) unsigned short VTl[32 * VSTR];   // V^T[d][j] bf16
    __shared__ float redl[4 * 32];
    __shared__ float invl[32];

    const size_t bh = (size_t)(b * H_ + h) * K_ * HD_;
    const unsigned short* KGb = KG + bh;
    const unsigned short* VGb = VG + bh;

    // ---- stage V^T into LDS (bf16 copy-transpose); zero pad regions ----
    for (int i = tid; i < K_ * 4; i += 256) {
        const int j = i >> 2, dc = i & 3;
        const short8v v = *(const short8v*)(VGb + i * 8);
        #pragma unroll
        for (int r = 0; r < 8; ++r)
            VTl[(dc*8 + r)*VSTR + j] = (unsigned short)v[r];
    }
    {   // P pad: j = 208..223 for all 32 q rows
        const int q = tid >> 3, cc = tid & 7;
        *(unsigned int*)&Pl[q * PSTR + 208 + cc * 2] = 0u;
    }
    for (int i = tid; i < 32 * 20; i += 256) {   // VT pad: j = 204..223
        VTl[(i / 20) * VSTR + 204 + (i % 20)] = 0;
    }

    // ---- QK^T via MFMA: wave w handles j-tiles {w, w+4, w+8, (w+12)} ----
    short8v qa[2];
    #pragma unroll
    for (int qt = 0; qt < 2; ++qt)
        qa[qt] = *(const short8v*)(Qb + (size_t)(b * S_ + q0 + qt*16 + c) * D_ + h * HD_ + g * 8);

    const int njt = (w == 0) ? 4 : 3;
    f32x4 acc[2][4];
    const f32x4 zf = {0.0f, 0.0f, 0.0f, 0.0f};
    #pragma unroll
    for (int qt = 0; qt < 2; ++qt)
        #pragma unroll
        for (int t = 0; t < 4; ++t) acc[qt][t] = zf;

    for (int t = 0; t < njt; ++t) {
        const int jt = w + 4 * t;
        const int jc = min(jt * 16 + c, K_ - 1);
        const short8v kb = *(const short8v*)(KGb + (size_t)jc * HD_ + g * 8);
        acc[0][t] = __builtin_amdgcn_mfma_f32_16x16x32_bf16(qa[0], kb, acc[0][t], 0, 0, 0);
        acc[1][t] = __builtin_amdgcn_mfma_f32_16x16x32_bf16(qa[1], kb, acc[1][t], 0, 0, 0);
    }

    // exp (fp32), write P (bf16), accumulate row-sums
    float rs[2][4] = {{0,0,0,0},{0,0,0,0}};
    for (int t = 0; t < njt; ++t) {
        const int jg = (w + 4 * t) * 16 + c;
        const bool val = (jg < K_);
        #pragma unroll
        for (int qt = 0; qt < 2; ++qt) {
            #pragma unroll
            for (int r = 0; r < 4; ++r) {
                const float e = val ? __expf(acc[qt][t][r] * SCALE_) : 0.0f;
                rs[qt][r] += e;
                Pl[(qt*16 + g*4 + r) * PSTR + jg] = f2bf(e);
            }
        }
    }
    #pragma unroll
    for (int qt = 0; qt < 2; ++qt)
        #pragma unroll
        for (int r = 0; r < 4; ++r) {
            float s = rs[qt][r];
            s += __shfl_xor(s, 1); s += __shfl_xor(s, 2);
            s += __shfl_xor(s, 4); s += __shfl_xor(s, 8);
            if (c == 0) redl[w * 32 + qt*16 + g*4 + r] = s;
        }

    __syncthreads();
    if (tid < 32)
        invl[tid] = 1.0f / (redl[tid] + redl[32 + tid] + redl[64 + tid] + redl[96 + tid]);
    __syncthreads();

    // ---- PV: O^T = V^T * P^T; wave w -> quadrant (dt = w>>1, qt2 = w&1) ----
    const int dt = w >> 1, qt2 = w & 1;
    f32x4 o = zf;
    const unsigned short* vb = &VTl[(dt*16 + c) * VSTR];
    const unsigned short* pb = &Pl[(qt2*16 + c) * PSTR];
    #pragma unroll
    for (int kt = 0; kt < 7; ++kt) {
        const short8v av = ld_bf8(vb + kt*32 + g*8);
        const short8v bv = ld_bf8(pb + kt*32 + g*8);
        o = __builtin_amdgcn_mfma_f32_16x16x32_bf16(av, bv, o, 0, 0, 0);
    }
    const float iv = invl[qt2*16 + c];
    const size_t oidx = (size_t)(b * S_ + q0 + qt2*16 + c) * D_ + h * HD_ + dt*16 + g*4;
    ushort4 hh, ll;
    {
        const float v0 = o[0]*iv, v1 = o[1]*iv, v2 = o[2]*iv, v3 = o[3]*iv;
        hh.x = f2bf(v0); ll.x = f2bf(v0 - bf2f(hh.x));
        hh.y = f2bf(v1); ll.y = f2bf(v1 - bf2f(hh.y));
        hh.z = f2bf(v2); ll.z = f2bf(v2 - bf2f(hh.z));
        hh.w = f2bf(v3); ll.w = f2bf(v3 - bf2f(hh.w));
    }
    *(ushort4*)(aoh + oidx) = hh;
    *(ushort4*)(aol + oidx) = ll;
}

extern "C" void kernel_launch(void* const* d_in, const int* in_sizes, int n_in,
                              void* d_out, int out_size, void* d_ws, size_t ws_size,
                              hipStream_t stream)
{
    const float* x     = (const float*)d_in[0];
    const float* w_in  = (const float*)d_in[1];
    const float* b_in  = (const float*)d_in[2];
    const float* w_out = (const float*)d_in[3];
    const float* b_out = (const float*)d_in[4];
    const float* gw1   = (const float*)d_in[5];
    const float* gb1   = (const float*)d_in[6];
    const float* gw2   = (const float*)d_in[7];
    // d_in[8] = gate_b2: constant inside monotone sigmoid -> doesn't affect top-k

    float* ws = (float*)d_ws;
    int* meta = (int*)(ws + OFF_META);
    int* kidx = (int*)(ws + OFF_KIDX);
    unsigned short* KG  = (unsigned short*)(ws + OFF_KG);
    unsigned short* VG  = (unsigned short*)(ws + OFF_VG);
    unsigned short* Qb  = (unsigned short*)(ws + OFF_Q);
    unsigned short* XH  = (unsigned short*)(ws + OFF_XH);
    unsigned short* XL  = (unsigned short*)(ws + OFF_XL);
    unsigned short* AOH = (unsigned short*)(ws + OFF_AOH);
    unsigned short* AOL = (unsigned short*)(ws + OFF_AOL);
    unsigned short* WQH = (unsigned short*)(ws + OFF_WQH);
    unsigned short* WQL = (unsigned short*)(ws + OFF_WQL);
    unsigned short* WOH = (unsigned short*)(ws + OFF_WOH);
    unsigned short* WOL = (unsigned short*)(ws + OFF_WOL);
    float* out = (float*)d_out;

    // gate + plane conversion (x, weights) + meta zero
    gate_kernel<<<B_ * S_ / 8, 256, 0, stream>>>(x, gw1, gb1, gw2, w_in, w_out, ws);
    // exact-rank top-k with ticketed emit
    rank_kernel<<<B_ * 128, 256, 0, stream>>>(ws + OFF_IMP, kidx, meta);
    // K/V projection -> bf16
    kv_kernel<<<dim3(51, B_), 256, 0, stream>>>(x, w_in, b_in, KG, VG, kidx);
    // Q = x @ w_in[0:256]^T + b_in  (bf16 output)
    gemm_kernel<true><<<dim3(B_ * S_ / 64, D_ / 64), 256, 0, stream>>>(
        XH, XL, WQH, WQL, b_in, nullptr, Qb);
    // attention
    attn_kernel<<<dim3(S_ / 32, H_, B_), 256, 0, stream>>>(KG, VG, Qb, AOH, AOL);
    // out = AO @ w_out^T + b_out  (fp32 output)
    gemm_kernel<false><<<dim3(B_ * S_ / 64, D_ / 64), 256, 0, stream>>>(
        AOH, AOL, WOH, WOL, b_out, out, nullptr);
}

// Round 6
// 146.124 us; speedup vs baseline: 2.4664x; 1.1199x over previous
//
#include <hip/hip_runtime.h>
#include <hip/hip_bf16.h>

// Problem constants
#define B_  4
#define S_  2048
#define D_  256
#define H_  8
#define HD_ 32
#define K_  204          // int(2048 * 0.1)
#define SCALE_ 0.17677669529663687f  // 1/sqrt(32)

// ---- workspace layout (float offsets) ----
// bf16 arrays stored as unsigned short; float-slot counts = shorts/2
#define OFF_IMP    0          // 8192 floats
#define OFF_META   8192       // 16 ints
#define OFF_KIDX   8208       // 1024 ints
#define OFF_KV     9232       // 417792 shorts [B][K_][512]: col = isV*256+h*32+d
#define OFF_Q      218128     // 2097152 shorts [B*S, D] bf16
#define OFF_XH     1266704    // 2097152 shorts: x hi plane
#define OFF_XL     2315280    // 2097152 shorts: x lo plane
#define OFF_AOH    3363856    // 2097152 shorts: attn-out hi plane
#define OFF_AOL    4412432    // 2097152 shorts: attn-out lo plane
#define OFF_WIH    5461008    // 196608 shorts: w_in (768x256) hi
#define OFF_WIL    5559312    // 196608 shorts: w_in lo
#define OFF_WOH    5657616    // 65536 shorts: w_out hi
#define OFF_WOL    5690384    // 65536 shorts: w_out lo
// total ~22.9 MB

#define GSTR 80    // gemm LDS row stride (shorts)
#define PSTR 228   // attn P row stride (bf16 elems)
#define VSTR 228   // attn V^T row stride

typedef __attribute__((ext_vector_type(8))) short short8v;
typedef __attribute__((ext_vector_type(4))) float f32x4;

static __device__ __forceinline__ unsigned short f2bf(float f) {
    unsigned int u = __float_as_uint(f);
    u += 0x7FFFu + ((u >> 16) & 1u);      // round-to-nearest-even
    return (unsigned short)(u >> 16);
}
static __device__ __forceinline__ float bf2f(unsigned short h) {
    return __uint_as_float((unsigned int)h << 16);
}
static __device__ __forceinline__ short8v ld_bf8(const unsigned short* p) {
    union { unsigned int u[4]; short8v v; } cv;
    const uint2 a  = *(const uint2*)(p);
    const uint2 b2 = *(const uint2*)(p + 4);
    cv.u[0] = a.x; cv.u[1] = a.y; cv.u[2] = b2.x; cv.u[3] = b2.y;
    return cv.v;
}
// split 8 contiguous fp32 -> bf16 hi/lo planes (16B store each)
static __device__ __forceinline__ void split_store8(
    const float* __restrict__ src, unsigned short* dh, unsigned short* dl)
{
    short8v h, l;
    #pragma unroll
    for (int e = 0; e < 8; ++e) {
        const float f = src[e];
        const unsigned short hh = f2bf(f);
        h[e] = (short)hh;
        l[e] = (short)f2bf(f - bf2f(hh));
    }
    *(short8v*)dh = h;
    *(short8v*)dl = l;
}

// ---------------- kernel 1: gate MLP + x/weight plane conversion ----------------
__global__ __launch_bounds__(256) void gate_kernel(
    const float* __restrict__ x, const float* __restrict__ gw1,
    const float* __restrict__ gb1, const float* __restrict__ gw2,
    const float* __restrict__ w_in, const float* __restrict__ w_out, float* ws)
{
    const int t0 = blockIdx.x * 8;
    const int tid = threadIdx.x;
    __shared__ __align__(16) float xs[8 * D_];
    __shared__ float hred[8 * 64];

    const float4* src = (const float4*)(x + (size_t)t0 * D_);
    ((float4*)xs)[tid]       = src[tid];
    ((float4*)xs)[tid + 256] = src[tid + 256];
    __syncthreads();

    // emit x bf16 hi/lo planes from the staged tile (no extra global reads)
    {
        unsigned short* XH = (unsigned short*)(ws + OFF_XH);
        unsigned short* XL = (unsigned short*)(ws + OFF_XL);
        split_store8(xs + tid * 8, XH + (size_t)t0 * D_ + tid * 8,
                                   XL + (size_t)t0 * D_ + tid * 8);
    }
    // blocks 0..127: convert w_in (768x256) and w_out (256x256) to planes
    if (blockIdx.x < 128) {
        const int e0 = blockIdx.x * 2048 + tid * 8;
        if (e0 < 196608) {
            split_store8(w_in + e0, (unsigned short*)(ws + OFF_WIH) + e0,
                                    (unsigned short*)(ws + OFF_WIL) + e0);
        } else {
            const int e = e0 - 196608;
            split_store8(w_out + e, (unsigned short*)(ws + OFF_WOH) + e,
                                    (unsigned short*)(ws + OFF_WOL) + e);
        }
    }
    if (blockIdx.x == 0 && tid < 16) ((int*)(ws + OFF_META))[tid] = 0;

    const int c = tid & 3, f = tid >> 2;
    float4 wv[16];
    const float4* wr = (const float4*)(gw1 + (size_t)f * D_) + c;
    #pragma unroll
    for (int j = 0; j < 16; ++j) wv[j] = wr[j * 4];
    const float bb = gb1[f], g2 = gw2[f];

    #pragma unroll
    for (int tk = 0; tk < 8; ++tk) {
        const float4* xr = (const float4*)(xs + tk * D_) + c;
        float a = 0.0f;
        #pragma unroll
        for (int j = 0; j < 16; ++j) {
            float4 xv = xr[j * 4];
            a += wv[j].x*xv.x + wv[j].y*xv.y + wv[j].z*xv.z + wv[j].w*xv.w;
        }
        a += __shfl_xor(a, 1);
        a += __shfl_xor(a, 2);
        if (c == 0) hred[tk * 64 + f] = fmaxf(a + bb, 0.0f) * g2;
    }
    __syncthreads();

    const int tk = tid >> 5, ln = tid & 31;
    float s = hred[tk * 64 + ln] + hred[tk * 64 + ln + 32];
    #pragma unroll
    for (int o = 16; o; o >>= 1) s += __shfl_xor(s, o, 32);
    if (ln == 0) ws[OFF_IMP + t0 + tk] = s;
}

// ---------------- kernel 2: exact rank -> ticketed compact index (unsorted) ----------------
// kept set identical to lax.top_k (rank = #greater + #equal-with-smaller-index < K).
// Slot order nondeterministic; attention is key-order invariant (validated r4/r5).
__global__ __launch_bounds__(256) void rank_kernel(
    const float* __restrict__ ws_imp, int* kidx, int* meta)
{
    const int b  = blockIdx.x >> 7;
    const int ic = blockIdx.x & 127;
    const int tid = threadIdx.x;
    __shared__ __align__(16) float vs[S_];
    const float* src = ws_imp + b * S_;
    #pragma unroll
    for (int cc = 0; cc < 2; ++cc)
        ((float4*)vs)[tid + cc*256] = ((const float4*)src)[tid + cc*256];
    __syncthreads();

    const int il = tid >> 4;
    const int c  = tid & 15;
    const int i  = ic * 16 + il;
    const float vi = vs[i];
    int gt = 0, eq = 0;
    const float4* v4 = (const float4*)vs + c * 32;
    #pragma unroll 8
    for (int t = 0; t < 32; ++t) {
        const int j4 = (t + c) & 31;
        float4 w = v4[j4];
        const int base = c * 128 + j4 * 4;
        gt += (w.x > vi); eq += (w.x == vi) && (base + 0 < i);
        gt += (w.y > vi); eq += (w.y == vi) && (base + 1 < i);
        gt += (w.z > vi); eq += (w.z == vi) && (base + 2 < i);
        gt += (w.w > vi); eq += (w.w == vi) && (base + 3 < i);
    }
    int r = gt + eq;
    r += __shfl_xor(r, 1);
    r += __shfl_xor(r, 2);
    r += __shfl_xor(r, 4);
    r += __shfl_xor(r, 8);
    if (c == 0 && r < K_) {
        const int p = atomicAdd(&meta[2 + b], 1);
        kidx[b * K_ + p] = i;
    }
}

// ---------------- kernel 3: K/V projection as gathered MFMA GEMM ----------------
// KV[b][j][eh] = sum_k x[tok_j][k] * w_in[256+eh][k] + b_in[256+eh], bf16 out.
// A rows gathered via kidx (clamped for pad rows 204..255; stores guarded).
// blockIdx.x: mt = x&3 (64-row tile), nt = x>>2 (64-col tile of 512); blockIdx.y = b.
__global__ __launch_bounds__(256) void kvg_kernel(
    const unsigned short* __restrict__ XH, const unsigned short* __restrict__ XL,
    const unsigned short* __restrict__ WKH, const unsigned short* __restrict__ WKL,
    const float* __restrict__ b_in, unsigned short* __restrict__ KV,
    const int* __restrict__ kidx)
{
    __shared__ __align__(16) unsigned short Ash[64 * GSTR];
    __shared__ __align__(16) unsigned short Asl[64 * GSTR];
    __shared__ __align__(16) unsigned short Bsh[64 * GSTR];
    __shared__ __align__(16) unsigned short Bsl[64 * GSTR];

    const int tid = threadIdx.x;
    const int b = blockIdx.y;
    const int m0 = (blockIdx.x & 3) * 64, n0 = (blockIdx.x >> 2) * 64;
    const int lane = tid & 63, w = tid >> 6;
    const int c = lane & 15, g = lane >> 4;
    const int mq = w >> 1, nq = w & 1;

    const f32x4 zf = {0.0f, 0.0f, 0.0f, 0.0f};
    f32x4 acc[2][2] = {{zf, zf}, {zf, zf}};

    const int srow = tid >> 2, sseg = tid & 3;
    const int tok = kidx[b * K_ + min(m0 + srow, K_ - 1)];
    const unsigned short* Aph = XH + ((size_t)b * S_ + tok) * D_ + sseg * 16;
    const unsigned short* Apl = XL + ((size_t)b * S_ + tok) * D_ + sseg * 16;
    const unsigned short* Bph = WKH + (size_t)(n0 + srow) * D_ + sseg * 16;
    const unsigned short* Bpl = WKL + (size_t)(n0 + srow) * D_ + sseg * 16;

    short8v arh[2], arl[2], brh[2], brl[2];
    #pragma unroll
    for (int u = 0; u < 2; ++u) {
        arh[u] = *(const short8v*)(Aph + u*8); arl[u] = *(const short8v*)(Apl + u*8);
        brh[u] = *(const short8v*)(Bph + u*8); brl[u] = *(const short8v*)(Bpl + u*8);
    }

    for (int k0 = 0; k0 < D_; k0 += 64) {
        __syncthreads();
        #pragma unroll
        for (int u = 0; u < 2; ++u) {
            *(short8v*)&Ash[srow*GSTR + sseg*16 + u*8] = arh[u];
            *(short8v*)&Asl[srow*GSTR + sseg*16 + u*8] = arl[u];
            *(short8v*)&Bsh[srow*GSTR + sseg*16 + u*8] = brh[u];
            *(short8v*)&Bsl[srow*GSTR + sseg*16 + u*8] = brl[u];
        }
        __syncthreads();
        if (k0 + 64 < D_) {
            #pragma unroll
            for (int u = 0; u < 2; ++u) {
                arh[u] = *(const short8v*)(Aph + k0 + 64 + u*8);
                arl[u] = *(const short8v*)(Apl + k0 + 64 + u*8);
                brh[u] = *(const short8v*)(Bph + k0 + 64 + u*8);
                brl[u] = *(const short8v*)(Bpl + k0 + 64 + u*8);
            }
        }
        #pragma unroll
        for (int ks = 0; ks < 2; ++ks) {
            short8v am[2][2], bm[2][2];
            #pragma unroll
            for (int t = 0; t < 2; ++t) {
                const int ra = (mq*32 + t*16 + c) * GSTR + ks*32 + g*8;
                am[t][0] = *(const short8v*)&Ash[ra];
                am[t][1] = *(const short8v*)&Asl[ra];
                const int rb = (nq*32 + t*16 + c) * GSTR + ks*32 + g*8;
                bm[t][0] = *(const short8v*)&Bsh[rb];
                bm[t][1] = *(const short8v*)&Bsl[rb];
            }
            #pragma unroll
            for (int mt = 0; mt < 2; ++mt)
                #pragma unroll
                for (int nt = 0; nt < 2; ++nt) {
                    acc[mt][nt] = __builtin_amdgcn_mfma_f32_16x16x32_bf16(am[mt][0], bm[nt][0], acc[mt][nt], 0, 0, 0);
                    acc[mt][nt] = __builtin_amdgcn_mfma_f32_16x16x32_bf16(am[mt][0], bm[nt][1], acc[mt][nt], 0, 0, 0);
                    acc[mt][nt] = __builtin_amdgcn_mfma_f32_16x16x32_bf16(am[mt][1], bm[nt][0], acc[mt][nt], 0, 0, 0);
                }
        }
    }
    #pragma unroll
    for (int nt = 0; nt < 2; ++nt) {
        const int n = n0 + nq*32 + nt*16 + c;              // 0..511
        const float bv = b_in[D_ + n];
        #pragma unroll
        for (int mt = 0; mt < 2; ++mt) {
            const int j = m0 + mq*32 + mt*16 + g*4;        // 0..255 (slot)
            #pragma unroll
            for (int r = 0; r < 4; ++r)
                if (j + r < K_)
                    KV[((size_t)b * K_ + j + r) * 512 + n] = f2bf(acc[mt][nt][r] + bv);
        }
    }
}

// ---------------- kernel 4: MFMA split-bf16 GEMM (pre-converted planes) ----------------
// C = A * W^T + bias; A = Ah+Al, W = Wh+Wl (bf16 planes in global).
// C ~= Ah*Wh + Ah*Wl + Al*Wh, fp32 accum. QOUT: bf16 out (Q); else fp32 (final).
template<bool QOUT>
__global__ __launch_bounds__(256) void gemm_kernel(
    const unsigned short* __restrict__ Ah, const unsigned short* __restrict__ Al,
    const unsigned short* __restrict__ Bh, const unsigned short* __restrict__ Bl,
    const float* __restrict__ bias, float* __restrict__ Cf,
    unsigned short* __restrict__ Cq)
{
    __shared__ __align__(16) unsigned short Ash[64 * GSTR];
    __shared__ __align__(16) unsigned short Asl[64 * GSTR];
    __shared__ __align__(16) unsigned short Bsh[64 * GSTR];
    __shared__ __align__(16) unsigned short Bsl[64 * GSTR];

    const int tid = threadIdx.x;
    const int m0 = blockIdx.x * 64, n0 = blockIdx.y * 64;
    const int lane = tid & 63, w = tid >> 6;
    const int c = lane & 15, g = lane >> 4;
    const int mq = w >> 1, nq = w & 1;

    const f32x4 zf = {0.0f, 0.0f, 0.0f, 0.0f};
    f32x4 acc[2][2] = {{zf, zf}, {zf, zf}};

    const int srow = tid >> 2, sseg = tid & 3;
    const unsigned short* Aph = Ah + (size_t)(m0 + srow) * D_ + sseg * 16;
    const unsigned short* Apl = Al + (size_t)(m0 + srow) * D_ + sseg * 16;
    const unsigned short* Bph = Bh + (size_t)(n0 + srow) * D_ + sseg * 16;
    const unsigned short* Bpl = Bl + (size_t)(n0 + srow) * D_ + sseg * 16;

    short8v arh[2], arl[2], brh[2], brl[2];
    #pragma unroll
    for (int u = 0; u < 2; ++u) {
        arh[u] = *(const short8v*)(Aph + u*8); arl[u] = *(const short8v*)(Apl + u*8);
        brh[u] = *(const short8v*)(Bph + u*8); brl[u] = *(const short8v*)(Bpl + u*8);
    }

    for (int k0 = 0; k0 < D_; k0 += 64) {
        __syncthreads();
        #pragma unroll
        for (int u = 0; u < 2; ++u) {
            *(short8v*)&Ash[srow*GSTR + sseg*16 + u*8] = arh[u];
            *(short8v*)&Asl[srow*GSTR + sseg*16 + u*8] = arl[u];
            *(short8v*)&Bsh[srow*GSTR + sseg*16 + u*8] = brh[u];
            *(short8v*)&Bsl[srow*GSTR + sseg*16 + u*8] = brl[u];
        }
        __syncthreads();
        if (k0 + 64 < D_) {
            #pragma unroll
            for (int u = 0; u < 2; ++u) {
                arh[u] = *(const short8v*)(Aph + k0 + 64 + u*8);
                arl[u] = *(const short8v*)(Apl + k0 + 64 + u*8);
                brh[u] = *(const short8v*)(Bph + k0 + 64 + u*8);
                brl[u] = *(const short8v*)(Bpl + k0 + 64 + u*8);
            }
        }
        #pragma unroll
        for (int ks = 0; ks < 2; ++ks) {
            short8v am[2][2], bm[2][2];
            #pragma unroll
            for (int t = 0; t < 2; ++t) {
                const int ra = (mq*32 + t*16 + c) * GSTR + ks*32 + g*8;
                am[t][0] = *(const short8v*)&Ash[ra];
                am[t][1] = *(const short8v*)&Asl[ra];
                const int rb = (nq*32 + t*16 + c) * GSTR + ks*32 + g*8;
                bm[t][0] = *(const short8v*)&Bsh[rb];
                bm[t][1] = *(const short8v*)&Bsl[rb];
            }
            #pragma unroll
            for (int mt = 0; mt < 2; ++mt)
                #pragma unroll
                for (int nt = 0; nt < 2; ++nt) {
                    acc[mt][nt] = __builtin_amdgcn_mfma_f32_16x16x32_bf16(am[mt][0], bm[nt][0], acc[mt][nt], 0, 0, 0);
                    acc[mt][nt] = __builtin_amdgcn_mfma_f32_16x16x32_bf16(am[mt][0], bm[nt][1], acc[mt][nt], 0, 0, 0);
                    acc[mt][nt] = __builtin_amdgcn_mfma_f32_16x16x32_bf16(am[mt][1], bm[nt][0], acc[mt][nt], 0, 0, 0);
                }
        }
    }
    #pragma unroll
    for (int nt = 0; nt < 2; ++nt) {
        const int n = n0 + nq*32 + nt*16 + c;
        const float bv = bias[n];
        #pragma unroll
        for (int mt = 0; mt < 2; ++mt) {
            const int m = m0 + mq*32 + mt*16 + g*4;
            #pragma unroll
            for (int r = 0; r < 4; ++r) {
                const float v = acc[mt][nt][r] + bv;
                if (QOUT) Cq[(size_t)(m + r) * D_ + n] = f2bf(v);
                else      Cf[(size_t)(m + r) * D_ + n] = v;
            }
        }
    }
}

// ---------------- kernel 5: attention core (bf16 in, planes out) ----------------
__global__ __launch_bounds__(256) void attn_kernel(
    const unsigned short* __restrict__ KV, const unsigned short* __restrict__ Qb,
    unsigned short* __restrict__ aoh, unsigned short* __restrict__ aol)
{
    const int b = blockIdx.z, h = blockIdx.y, q0 = blockIdx.x * 32;
    const int tid = threadIdx.x;
    const int lane = tid & 63, w = tid >> 6;
    const int c = lane & 15, g = lane >> 4;

    __shared__ __align__(16) unsigned short Pl[32 * PSTR];    // P[q][j] bf16
    __shared__ __align__(16) unsigned short VTl[32 * VSTR];   // V^T[d][j] bf16
    __shared__ float redl[4 * 32];
    __shared__ float invl[32];

    const unsigned short* KVb = KV + (size_t)b * K_ * 512;
    // K row j: KVb + j*512 + h*32 + d ; V row j: + 256

    // ---- stage V^T into LDS (bf16 copy-transpose); zero pad regions ----
    for (int i = tid; i < K_ * 4; i += 256) {
        const int j = i >> 2, dc = i & 3;
        const short8v v = *(const short8v*)(KVb + (size_t)j * 512 + 256 + h * HD_ + dc * 8);
        #pragma unroll
        for (int r = 0; r < 8; ++r)
            VTl[(dc*8 + r)*VSTR + j] = (unsigned short)v[r];
    }
    {   // P pad: j = 208..223 for all 32 q rows
        const int q = tid >> 3, cc = tid & 7;
        *(unsigned int*)&Pl[q * PSTR + 208 + cc * 2] = 0u;
    }
    for (int i = tid; i < 32 * 20; i += 256) {   // VT pad: j = 204..223
        VTl[(i / 20) * VSTR + 204 + (i % 20)] = 0;
    }

    // ---- QK^T via MFMA: wave w handles j-tiles {w, w+4, w+8, (w+12)} ----
    short8v qa[2];
    #pragma unroll
    for (int qt = 0; qt < 2; ++qt)
        qa[qt] = *(const short8v*)(Qb + (size_t)(b * S_ + q0 + qt*16 + c) * D_ + h * HD_ + g * 8);

    const int njt = (w == 0) ? 4 : 3;
    f32x4 acc[2][4];
    const f32x4 zf = {0.0f, 0.0f, 0.0f, 0.0f};
    #pragma unroll
    for (int qt = 0; qt < 2; ++qt)
        #pragma unroll
        for (int t = 0; t < 4; ++t) acc[qt][t] = zf;

    for (int t = 0; t < njt; ++t) {
        const int jt = w + 4 * t;
        const int jc = min(jt * 16 + c, K_ - 1);
        const short8v kb = *(const short8v*)(KVb + (size_t)jc * 512 + h * HD_ + g * 8);
        acc[0][t] = __builtin_amdgcn_mfma_f32_16x16x32_bf16(qa[0], kb, acc[0][t], 0, 0, 0);
        acc[1][t] = __builtin_amdgcn_mfma_f32_16x16x32_bf16(qa[1], kb, acc[1][t], 0, 0, 0);
    }

    // exp (fp32), write P (bf16), accumulate row-sums
    float rs[2][4] = {{0,0,0,0},{0,0,0,0}};
    for (int t = 0; t < njt; ++t) {
        const int jg = (w + 4 * t) * 16 + c;
        const bool val = (jg < K_);
        #pragma unroll
        for (int qt = 0; qt < 2; ++qt) {
            #pragma unroll
            for (int r = 0; r < 4; ++r) {
                const float e = val ? __expf(acc[qt][t][r] * SCALE_) : 0.0f;
                rs[qt][r] += e;
                Pl[(qt*16 + g*4 + r) * PSTR + jg] = f2bf(e);
            }
        }
    }
    #pragma unroll
    for (int qt = 0; qt < 2; ++qt)
        #pragma unroll
        for (int r = 0; r < 4; ++r) {
            float s = rs[qt][r];
            s += __shfl_xor(s, 1); s += __shfl_xor(s, 2);
            s += __shfl_xor(s, 4); s += __shfl_xor(s, 8);
            if (c == 0) redl[w * 32 + qt*16 + g*4 + r] = s;
        }

    __syncthreads();
    if (tid < 32)
        invl[tid] = 1.0f / (redl[tid] + redl[32 + tid] + redl[64 + tid] + redl[96 + tid]);
    __syncthreads();

    // ---- PV: O^T = V^T * P^T; wave w -> quadrant (dt = w>>1, qt2 = w&1) ----
    const int dt = w >> 1, qt2 = w & 1;
    f32x4 o = zf;
    const unsigned short* vb = &VTl[(dt*16 + c) * VSTR];
    const unsigned short* pb = &Pl[(qt2*16 + c) * PSTR];
    #pragma unroll
    for (int kt = 0; kt < 7; ++kt) {
        const short8v av = ld_bf8(vb + kt*32 + g*8);
        const short8v bv = ld_bf8(pb + kt*32 + g*8);
        o = __builtin_amdgcn_mfma_f32_16x16x32_bf16(av, bv, o, 0, 0, 0);
    }
    const float iv = invl[qt2*16 + c];
    const size_t oidx = (size_t)(b * S_ + q0 + qt2*16 + c) * D_ + h * HD_ + dt*16 + g*4;
    ushort4 hh, ll;
    {
        const float v0 = o[0]*iv, v1 = o[1]*iv, v2 = o[2]*iv, v3 = o[3]*iv;
        hh.x = f2bf(v0); ll.x = f2bf(v0 - bf2f(hh.x));
        hh.y = f2bf(v1); ll.y = f2bf(v1 - bf2f(hh.y));
        hh.z = f2bf(v2); ll.z = f2bf(v2 - bf2f(hh.z));
        hh.w = f2bf(v3); ll.w = f2bf(v3 - bf2f(hh.w));
    }
    *(ushort4*)(aoh + oidx) = hh;
    *(ushort4*)(aol + oidx) = ll;
}

extern "C" void kernel_launch(void* const* d_in, const int* in_sizes, int n_in,
                              void* d_out, int out_size, void* d_ws, size_t ws_size,
                              hipStream_t stream)
{
    const float* x     = (const float*)d_in[0];
    const float* w_in  = (const float*)d_in[1];
    const float* b_in  = (const float*)d_in[2];
    const float* w_out = (const float*)d_in[3];
    const float* b_out = (const float*)d_in[4];
    const float* gw1   = (const float*)d_in[5];
    const float* gb1   = (const float*)d_in[6];
    const float* gw2   = (const float*)d_in[7];
    // d_in[8] = gate_b2: constant inside monotone sigmoid -> doesn't affect top-k

    float* ws = (float*)d_ws;
    int* meta = (int*)(ws + OFF_META);
    int* kidx = (int*)(ws + OFF_KIDX);
    unsigned short* KV  = (unsigned short*)(ws + OFF_KV);
    unsigned short* Qb  = (unsigned short*)(ws + OFF_Q);
    unsigned short* XH  = (unsigned short*)(ws + OFF_XH);
    unsigned short* XL  = (unsigned short*)(ws + OFF_XL);
    unsigned short* AOH = (unsigned short*)(ws + OFF_AOH);
    unsigned short* AOL = (unsigned short*)(ws + OFF_AOL);
    unsigned short* WIH = (unsigned short*)(ws + OFF_WIH);
    unsigned short* WIL = (unsigned short*)(ws + OFF_WIL);
    unsigned short* WOH = (unsigned short*)(ws + OFF_WOH);
    unsigned short* WOL = (unsigned short*)(ws + OFF_WOL);
    float* out = (float*)d_out;

    // gate + plane conversion (x, w_in, w_out) + meta zero
    gate_kernel<<<B_ * S_ / 8, 256, 0, stream>>>(x, gw1, gb1, gw2, w_in, w_out, ws);
    // exact-rank top-k with ticketed emit
    rank_kernel<<<B_ * 128, 256, 0, stream>>>(ws + OFF_IMP, kidx, meta);
    // K/V projection as gathered MFMA GEMM (w_in rows 256..768 planes)
    kvg_kernel<<<dim3(32, B_), 256, 0, stream>>>(
        XH, XL, WIH + 65536, WIL + 65536, b_in, KV, kidx);
    // Q = x @ w_in[0:256]^T + b_in  (bf16 output)
    gemm_kernel<true><<<dim3(B_ * S_ / 64, D_ / 64), 256, 0, stream>>>(
        XH, XL, WIH, WIL, b_in, nullptr, Qb);
    // attention
    attn_kernel<<<dim3(S_ / 32, H_, B_), 256, 0, stream>>>(KV, Qb, AOH, AOL);
    // out = AO @ w_out^T + b_out  (fp32 output)
    gemm_kernel<false><<<dim3(B_ * S_ / 64, D_ / 64), 256, 0, stream>>>(
        AOH, AOL, WOH, WOL, b_out, out, nullptr);
}

// Round 7
// 143.476 us; speedup vs baseline: 2.5119x; 1.0185x over previous
//
#include <hip/hip_runtime.h>
#include <hip/hip_bf16.h>

// Problem constants
#define B_  4
#define S_  2048
#define D_  256
#define H_  8
#define HD_ 32
#define K_  204          // int(2048 * 0.1)
#define SCALE_ 0.17677669529663687f  // 1/sqrt(32)

// ---- workspace layout (float offsets; all %4==0 -> 16B aligned) ----
#define OFF_IMP    0          // 8192 floats
#define OFF_META   8192       // 16 ints
#define OFF_KIDX   8208       // 1024 ints
#define OFF_KG     9232       // 208896 shorts [B][K_][256] bf16 (col = h*32+d)
#define OFF_VT     113680     // 229376 shorts [B][256][224] bf16 (V^T, cols 204.. zeroed)
#define OFF_Q      228368     // 2097152 shorts [B*S, D] bf16
#define OFF_XH     1276944    // 2097152 shorts: x hi plane
#define OFF_XL     2325520    // 2097152 shorts: x lo plane
#define OFF_AOH    3374096    // 2097152 shorts: attn-out hi plane
#define OFF_AOL    4422672    // 2097152 shorts: attn-out lo plane
#define OFF_WIH    5471248    // 196608 shorts: w_in (768x256) hi
#define OFF_WIL    5569552    // 196608 shorts: w_in lo
#define OFF_WOH    5667856    // 65536 shorts: w_out hi
#define OFF_WOL    5700624    // 65536 shorts: w_out lo
// total ~22.9 MB

#define GSTR 80    // gemm LDS row stride (shorts)
#define PSTR 228   // attn P row stride (shorts)
#define VSTR 232   // attn V^T LDS row stride (shorts; 464B = 16B-aligned rows)

typedef __attribute__((ext_vector_type(8))) short short8v;
typedef __attribute__((ext_vector_type(4))) float f32x4;

static __device__ __forceinline__ unsigned short f2bf(float f) {
    unsigned int u = __float_as_uint(f);
    u += 0x7FFFu + ((u >> 16) & 1u);      // round-to-nearest-even
    return (unsigned short)(u >> 16);
}
static __device__ __forceinline__ float bf2f(unsigned short h) {
    return __uint_as_float((unsigned int)h << 16);
}
static __device__ __forceinline__ short8v ld_bf8(const unsigned short* p) {
    union { unsigned int u[4]; short8v v; } cv;
    const uint2 a  = *(const uint2*)(p);
    const uint2 b2 = *(const uint2*)(p + 4);
    cv.u[0] = a.x; cv.u[1] = a.y; cv.u[2] = b2.x; cv.u[3] = b2.y;
    return cv.v;
}
// split 8 contiguous fp32 -> bf16 hi/lo planes (16B store each)
static __device__ __forceinline__ void split_store8(
    const float* __restrict__ src, unsigned short* dh, unsigned short* dl)
{
    short8v h, l;
    #pragma unroll
    for (int e = 0; e < 8; ++e) {
        const float f = src[e];
        const unsigned short hh = f2bf(f);
        h[e] = (short)hh;
        l[e] = (short)f2bf(f - bf2f(hh));
    }
    *(short8v*)dh = h;
    *(short8v*)dl = l;
}

// ---------------- kernel 1: gate MLP + x/weight plane conversion ----------------
__global__ __launch_bounds__(256) void gate_kernel(
    const float* __restrict__ x, const float* __restrict__ gw1,
    const float* __restrict__ gb1, const float* __restrict__ gw2,
    const float* __restrict__ w_in, const float* __restrict__ w_out, float* ws)
{
    const int t0 = blockIdx.x * 8;
    const int tid = threadIdx.x;
    __shared__ __align__(16) float xs[8 * D_];
    __shared__ float hred[8 * 64];

    const float4* src = (const float4*)(x + (size_t)t0 * D_);
    ((float4*)xs)[tid]       = src[tid];
    ((float4*)xs)[tid + 256] = src[tid + 256];
    __syncthreads();

    // emit x bf16 hi/lo planes from the staged tile (no extra global reads)
    {
        unsigned short* XH = (unsigned short*)(ws + OFF_XH);
        unsigned short* XL = (unsigned short*)(ws + OFF_XL);
        split_store8(xs + tid * 8, XH + (size_t)t0 * D_ + tid * 8,
                                   XL + (size_t)t0 * D_ + tid * 8);
    }
    // blocks 0..127: convert w_in (768x256) and w_out (256x256) to planes
    if (blockIdx.x < 128) {
        const int e0 = blockIdx.x * 2048 + tid * 8;
        if (e0 < 196608) {
            split_store8(w_in + e0, (unsigned short*)(ws + OFF_WIH) + e0,
                                    (unsigned short*)(ws + OFF_WIL) + e0);
        } else {
            const int e = e0 - 196608;
            split_store8(w_out + e, (unsigned short*)(ws + OFF_WOH) + e,
                                    (unsigned short*)(ws + OFF_WOL) + e);
        }
    }
    if (blockIdx.x == 0 && tid < 16) ((int*)(ws + OFF_META))[tid] = 0;

    const int c = tid & 3, f = tid >> 2;
    float4 wv[16];
    const float4* wr = (const float4*)(gw1 + (size_t)f * D_) + c;
    #pragma unroll
    for (int j = 0; j < 16; ++j) wv[j] = wr[j * 4];
    const float bb = gb1[f], g2 = gw2[f];

    #pragma unroll
    for (int tk = 0; tk < 8; ++tk) {
        const float4* xr = (const float4*)(xs + tk * D_) + c;
        float a = 0.0f;
        #pragma unroll
        for (int j = 0; j < 16; ++j) {
            float4 xv = xr[j * 4];
            a += wv[j].x*xv.x + wv[j].y*xv.y + wv[j].z*xv.z + wv[j].w*xv.w;
        }
        a += __shfl_xor(a, 1);
        a += __shfl_xor(a, 2);
        if (c == 0) hred[tk * 64 + f] = fmaxf(a + bb, 0.0f) * g2;
    }
    __syncthreads();

    const int tk = tid >> 5, ln = tid & 31;
    float s = hred[tk * 64 + ln] + hred[tk * 64 + ln + 32];
    #pragma unroll
    for (int o = 16; o; o >>= 1) s += __shfl_xor(s, o, 32);
    if (ln == 0) ws[OFF_IMP + t0 + tk] = s;
}

// ---------------- kernel 2: exact rank -> ticketed compact index (unsorted) ----------------
// kept set identical to lax.top_k (rank = #greater + #equal-with-smaller-index < K).
// Slot order nondeterministic; attention is key-order invariant (validated r4/r5/r6).
__global__ __launch_bounds__(256) void rank_kernel(
    const float* __restrict__ ws_imp, int* kidx, int* meta)
{
    const int b  = blockIdx.x >> 7;
    const int ic = blockIdx.x & 127;
    const int tid = threadIdx.x;
    __shared__ __align__(16) float vs[S_];
    const float* src = ws_imp + b * S_;
    #pragma unroll
    for (int cc = 0; cc < 2; ++cc)
        ((float4*)vs)[tid + cc*256] = ((const float4*)src)[tid + cc*256];
    __syncthreads();

    const int il = tid >> 4;
    const int c  = tid & 15;
    const int i  = ic * 16 + il;
    const float vi = vs[i];
    int gt = 0, eq = 0;
    const float4* v4 = (const float4*)vs + c * 32;
    #pragma unroll 8
    for (int t = 0; t < 32; ++t) {
        const int j4 = (t + c) & 31;
        float4 w = v4[j4];
        const int base = c * 128 + j4 * 4;
        gt += (w.x > vi); eq += (w.x == vi) && (base + 0 < i);
        gt += (w.y > vi); eq += (w.y == vi) && (base + 1 < i);
        gt += (w.z > vi); eq += (w.z == vi) && (base + 2 < i);
        gt += (w.w > vi); eq += (w.w == vi) && (base + 3 < i);
    }
    int r = gt + eq;
    r += __shfl_xor(r, 1);
    r += __shfl_xor(r, 2);
    r += __shfl_xor(r, 4);
    r += __shfl_xor(r, 8);
    if (c == 0 && r < K_) {
        const int p = atomicAdd(&meta[2 + b], 1);
        kidx[b * K_ + p] = i;
    }
}

// ---------------- kernel 3: fused projection (Q GEMM + gathered KV GEMM) ----------------
// blockIdx.x < 128: Q tile  (m0 = x*64 of 8192 rows, n0 = y*64 of 256)
// else: KV tile for batch y (m = key slot of 256-pad, n = 512 cols; w_in rows 256..768)
// Split-bf16: C ~= Ah*Wh + Ah*Wl + Al*Wh, fp32 accum.
// K out: KG[b][j][256]; V out: transposed VT[b][d][224] with cols 204..223 zeroed.
__global__ __launch_bounds__(256) void proj_kernel(
    const unsigned short* __restrict__ XH, const unsigned short* __restrict__ XL,
    const unsigned short* __restrict__ WIH, const unsigned short* __restrict__ WIL,
    const float* __restrict__ b_in, unsigned short* __restrict__ Qb,
    unsigned short* __restrict__ KG, unsigned short* __restrict__ VTg,
    const int* __restrict__ kidx)
{
    __shared__ __align__(16) unsigned short Ash[64 * GSTR];
    __shared__ __align__(16) unsigned short Asl[64 * GSTR];
    __shared__ __align__(16) unsigned short Bsh[64 * GSTR];
    __shared__ __align__(16) unsigned short Bsl[64 * GSTR];

    const int tid = threadIdx.x;
    const bool isQ = (blockIdx.x < 128);
    const int lane = tid & 63, w = tid >> 6;
    const int c = lane & 15, g = lane >> 4;
    const int mq = w >> 1, nq = w & 1;
    const int srow = tid >> 2, sseg = tid & 3;

    int m0, n0, b = blockIdx.y;
    size_t arow;   // A-plane row index
    int brow;      // w_in row index
    if (isQ) {
        m0 = blockIdx.x * 64; n0 = blockIdx.y * 64;
        arow = (size_t)(m0 + srow);
        brow = n0 + srow;
    } else {
        const int kx = blockIdx.x - 128;
        m0 = (kx & 3) * 64; n0 = (kx >> 2) * 64;
        const int tok = kidx[b * K_ + min(m0 + srow, K_ - 1)];
        arow = (size_t)b * S_ + tok;
        brow = D_ + n0 + srow;
    }
    const unsigned short* Aph = XH + arow * D_ + sseg * 16;
    const unsigned short* Apl = XL + arow * D_ + sseg * 16;
    const unsigned short* Bph = WIH + (size_t)brow * D_ + sseg * 16;
    const unsigned short* Bpl = WIL + (size_t)brow * D_ + sseg * 16;

    const f32x4 zf = {0.0f, 0.0f, 0.0f, 0.0f};
    f32x4 acc[2][2] = {{zf, zf}, {zf, zf}};

    short8v arh[2], arl[2], brh[2], brl[2];
    #pragma unroll
    for (int u = 0; u < 2; ++u) {
        arh[u] = *(const short8v*)(Aph + u*8); arl[u] = *(const short8v*)(Apl + u*8);
        brh[u] = *(const short8v*)(Bph + u*8); brl[u] = *(const short8v*)(Bpl + u*8);
    }

    for (int k0 = 0; k0 < D_; k0 += 64) {
        __syncthreads();
        #pragma unroll
        for (int u = 0; u < 2; ++u) {
            *(short8v*)&Ash[srow*GSTR + sseg*16 + u*8] = arh[u];
            *(short8v*)&Asl[srow*GSTR + sseg*16 + u*8] = arl[u];
            *(short8v*)&Bsh[srow*GSTR + sseg*16 + u*8] = brh[u];
            *(short8v*)&Bsl[srow*GSTR + sseg*16 + u*8] = brl[u];
        }
        __syncthreads();
        if (k0 + 64 < D_) {
            #pragma unroll
            for (int u = 0; u < 2; ++u) {
                arh[u] = *(const short8v*)(Aph + k0 + 64 + u*8);
                arl[u] = *(const short8v*)(Apl + k0 + 64 + u*8);
                brh[u] = *(const short8v*)(Bph + k0 + 64 + u*8);
                brl[u] = *(const short8v*)(Bpl + k0 + 64 + u*8);
            }
        }
        #pragma unroll
        for (int ks = 0; ks < 2; ++ks) {
            short8v am[2][2], bm[2][2];
            #pragma unroll
            for (int t = 0; t < 2; ++t) {
                const int ra = (mq*32 + t*16 + c) * GSTR + ks*32 + g*8;
                am[t][0] = *(const short8v*)&Ash[ra];
                am[t][1] = *(const short8v*)&Asl[ra];
                const int rb = (nq*32 + t*16 + c) * GSTR + ks*32 + g*8;
                bm[t][0] = *(const short8v*)&Bsh[rb];
                bm[t][1] = *(const short8v*)&Bsl[rb];
            }
            #pragma unroll
            for (int mt = 0; mt < 2; ++mt)
                #pragma unroll
                for (int nt = 0; nt < 2; ++nt) {
                    acc[mt][nt] = __builtin_amdgcn_mfma_f32_16x16x32_bf16(am[mt][0], bm[nt][0], acc[mt][nt], 0, 0, 0);
                    acc[mt][nt] = __builtin_amdgcn_mfma_f32_16x16x32_bf16(am[mt][0], bm[nt][1], acc[mt][nt], 0, 0, 0);
                    acc[mt][nt] = __builtin_amdgcn_mfma_f32_16x16x32_bf16(am[mt][1], bm[nt][0], acc[mt][nt], 0, 0, 0);
                }
        }
    }

    if (isQ) {
        #pragma unroll
        for (int nt = 0; nt < 2; ++nt) {
            const int n = n0 + nq*32 + nt*16 + c;
            const float bv = b_in[n];
            #pragma unroll
            for (int mt = 0; mt < 2; ++mt) {
                const int m = m0 + mq*32 + mt*16 + g*4;
                #pragma unroll
                for (int r = 0; r < 4; ++r)
                    Qb[(size_t)(m + r) * D_ + n] = f2bf(acc[mt][nt][r] + bv);
            }
        }
    } else {
        #pragma unroll
        for (int nt = 0; nt < 2; ++nt) {
            const int n = n0 + nq*32 + nt*16 + c;           // 0..511
            const float bv = b_in[D_ + n];
            #pragma unroll
            for (int mt = 0; mt < 2; ++mt) {
                const int j = m0 + mq*32 + mt*16 + g*4;     // key slot
                #pragma unroll
                for (int r = 0; r < 4; ++r) {
                    const int jj = j + r;
                    if (n < 256) {
                        if (jj < K_)
                            KG[((size_t)b * K_ + jj) * 256 + n] = f2bf(acc[mt][nt][r] + bv);
                    } else {
                        if (jj < 224)
                            VTg[((size_t)b * 256 + (n - 256)) * 224 + jj] =
                                (jj < K_) ? f2bf(acc[mt][nt][r] + bv) : (unsigned short)0;
                    }
                }
            }
        }
    }
}

// ---------------- kernel 4: MFMA split-bf16 GEMM (out projection, fp32 out) ----------------
__global__ __launch_bounds__(256) void gemm_kernel(
    const unsigned short* __restrict__ Ah, const unsigned short* __restrict__ Al,
    const unsigned short* __restrict__ Bh, const unsigned short* __restrict__ Bl,
    const float* __restrict__ bias, float* __restrict__ Cf)
{
    __shared__ __align__(16) unsigned short Ash[64 * GSTR];
    __shared__ __align__(16) unsigned short Asl[64 * GSTR];
    __shared__ __align__(16) unsigned short Bsh[64 * GSTR];
    __shared__ __align__(16) unsigned short Bsl[64 * GSTR];

    const int tid = threadIdx.x;
    const int m0 = blockIdx.x * 64, n0 = blockIdx.y * 64;
    const int lane = tid & 63, w = tid >> 6;
    const int c = lane & 15, g = lane >> 4;
    const int mq = w >> 1, nq = w & 1;

    const f32x4 zf = {0.0f, 0.0f, 0.0f, 0.0f};
    f32x4 acc[2][2] = {{zf, zf}, {zf, zf}};

    const int srow = tid >> 2, sseg = tid & 3;
    const unsigned short* Aph = Ah + (size_t)(m0 + srow) * D_ + sseg * 16;
    const unsigned short* Apl = Al + (size_t)(m0 + srow) * D_ + sseg * 16;
    const unsigned short* Bph = Bh + (size_t)(n0 + srow) * D_ + sseg * 16;
    const unsigned short* Bpl = Bl + (size_t)(n0 + srow) * D_ + sseg * 16;

    short8v arh[2], arl[2], brh[2], brl[2];
    #pragma unroll
    for (int u = 0; u < 2; ++u) {
        arh[u] = *(const short8v*)(Aph + u*8); arl[u] = *(const short8v*)(Apl + u*8);
        brh[u] = *(const short8v*)(Bph + u*8); brl[u] = *(const short8v*)(Bpl + u*8);
    }

    for (int k0 = 0; k0 < D_; k0 += 64) {
        __syncthreads();
        #pragma unroll
        for (int u = 0; u < 2; ++u) {
            *(short8v*)&Ash[srow*GSTR + sseg*16 + u*8] = arh[u];
            *(short8v*)&Asl[srow*GSTR + sseg*16 + u*8] = arl[u];
            *(short8v*)&Bsh[srow*GSTR + sseg*16 + u*8] = brh[u];
            *(short8v*)&Bsl[srow*GSTR + sseg*16 + u*8] = brl[u];
        }
        __syncthreads();
        if (k0 + 64 < D_) {
            #pragma unroll
            for (int u = 0; u < 2; ++u) {
                arh[u] = *(const short8v*)(Aph + k0 + 64 + u*8);
                arl[u] = *(const short8v*)(Apl + k0 + 64 + u*8);
                brh[u] = *(const short8v*)(Bph + k0 + 64 + u*8);
                brl[u] = *(const short8v*)(Bpl + k0 + 64 + u*8);
            }
        }
        #pragma unroll
        for (int ks = 0; ks < 2; ++ks) {
            short8v am[2][2], bm[2][2];
            #pragma unroll
            for (int t = 0; t < 2; ++t) {
                const int ra = (mq*32 + t*16 + c) * GSTR + ks*32 + g*8;
                am[t][0] = *(const short8v*)&Ash[ra];
                am[t][1] = *(const short8v*)&Asl[ra];
                const int rb = (nq*32 + t*16 + c) * GSTR + ks*32 + g*8;
                bm[t][0] = *(const short8v*)&Bsh[rb];
                bm[t][1] = *(const short8v*)&Bsl[rb];
            }
            #pragma unroll
            for (int mt = 0; mt < 2; ++mt)
                #pragma unroll
                for (int nt = 0; nt < 2; ++nt) {
                    acc[mt][nt] = __builtin_amdgcn_mfma_f32_16x16x32_bf16(am[mt][0], bm[nt][0], acc[mt][nt], 0, 0, 0);
                    acc[mt][nt] = __builtin_amdgcn_mfma_f32_16x16x32_bf16(am[mt][0], bm[nt][1], acc[mt][nt], 0, 0, 0);
                    acc[mt][nt] = __builtin_amdgcn_mfma_f32_16x16x32_bf16(am[mt][1], bm[nt][0], acc[mt][nt], 0, 0, 0);
                }
        }
    }
    #pragma unroll
    for (int nt = 0; nt < 2; ++nt) {
        const int n = n0 + nq*32 + nt*16 + c;
        const float bv = bias[n];
        #pragma unroll
        for (int mt = 0; mt < 2; ++mt) {
            const int m = m0 + mq*32 + mt*16 + g*4;
            #pragma unroll
            for (int r = 0; r < 4; ++r)
                Cf[(size_t)(m + r) * D_ + n] = acc[mt][nt][r] + bv;
        }
    }
}

// ---------------- kernel 5: attention core (bf16 in, planes out) ----------------
__global__ __launch_bounds__(256) void attn_kernel(
    const unsigned short* __restrict__ KG, const unsigned short* __restrict__ VTg,
    const unsigned short* __restrict__ Qb,
    unsigned short* __restrict__ aoh, unsigned short* __restrict__ aol)
{
    const int b = blockIdx.z, h = blockIdx.y, q0 = blockIdx.x * 32;
    const int tid = threadIdx.x;
    const int lane = tid & 63, w = tid >> 6;
    const int c = lane & 15, g = lane >> 4;

    __shared__ __align__(16) unsigned short Pl[32 * PSTR];    // P[q][j] bf16
    __shared__ __align__(16) unsigned short VTl[32 * VSTR];   // V^T[d][j] bf16
    __shared__ float redl[4 * 32];
    __shared__ float invl[32];

    const unsigned short* KGb = KG + (size_t)b * K_ * 256;

    // ---- stage V^T rows (pre-transposed, pre-padded in global): vector copy ----
    {
        const unsigned short* vsrc = VTg + ((size_t)b * 256 + h * HD_) * 224;
        for (int i = tid; i < 32 * 28; i += 256) {
            const int d = i / 28, seg = i % 28;
            *(short8v*)&VTl[d * VSTR + seg * 8] = *(const short8v*)(vsrc + d * 224 + seg * 8);
        }
    }
    {   // P pad: j = 208..223 for all 32 q rows
        const int q = tid >> 3, cc = tid & 7;
        *(unsigned int*)&Pl[q * PSTR + 208 + cc * 2] = 0u;
    }

    // ---- QK^T via MFMA: wave w handles j-tiles {w, w+4, w+8, (w+12)} ----
    short8v qa[2];
    #pragma unroll
    for (int qt = 0; qt < 2; ++qt)
        qa[qt] = *(const short8v*)(Qb + (size_t)(b * S_ + q0 + qt*16 + c) * D_ + h * HD_ + g * 8);

    const int njt = (w == 0) ? 4 : 3;
    f32x4 acc[2][4];
    const f32x4 zf = {0.0f, 0.0f, 0.0f, 0.0f};
    #pragma unroll
    for (int qt = 0; qt < 2; ++qt)
        #pragma unroll
        for (int t = 0; t < 4; ++t) acc[qt][t] = zf;

    for (int t = 0; t < njt; ++t) {
        const int jt = w + 4 * t;
        const int jc = min(jt * 16 + c, K_ - 1);
        const short8v kb = *(const short8v*)(KGb + (size_t)jc * 256 + h * HD_ + g * 8);
        acc[0][t] = __builtin_amdgcn_mfma_f32_16x16x32_bf16(qa[0], kb, acc[0][t], 0, 0, 0);
        acc[1][t] = __builtin_amdgcn_mfma_f32_16x16x32_bf16(qa[1], kb, acc[1][t], 0, 0, 0);
    }

    // exp (fp32), write P (bf16), accumulate row-sums
    float rs[2][4] = {{0,0,0,0},{0,0,0,0}};
    for (int t = 0; t < njt; ++t) {
        const int jg = (w + 4 * t) * 16 + c;
        const bool val = (jg < K_);
        #pragma unroll
        for (int qt = 0; qt < 2; ++qt) {
            #pragma unroll
            for (int r = 0; r < 4; ++r) {
                const float e = val ? __expf(acc[qt][t][r] * SCALE_) : 0.0f;
                rs[qt][r] += e;
                Pl[(qt*16 + g*4 + r) * PSTR + jg] = f2bf(e);
            }
        }
    }
    #pragma unroll
    for (int qt = 0; qt < 2; ++qt)
        #pragma unroll
        for (int r = 0; r < 4; ++r) {
            float s = rs[qt][r];
            s += __shfl_xor(s, 1); s += __shfl_xor(s, 2);
            s += __shfl_xor(s, 4); s += __shfl_xor(s, 8);
            if (c == 0) redl[w * 32 + qt*16 + g*4 + r] = s;
        }

    __syncthreads();
    if (tid < 32)
        invl[tid] = 1.0f / (redl[tid] + redl[32 + tid] + redl[64 + tid] + redl[96 + tid]);
    __syncthreads();

    // ---- PV: O^T = V^T * P^T; wave w -> quadrant (dt = w>>1, qt2 = w&1) ----
    const int dt = w >> 1, qt2 = w & 1;
    f32x4 o = zf;
    const unsigned short* vb = &VTl[(dt*16 + c) * VSTR];
    const unsigned short* pb = &Pl[(qt2*16 + c) * PSTR];
    #pragma unroll
    for (int kt = 0; kt < 7; ++kt) {
        const short8v av = ld_bf8(vb + kt*32 + g*8);
        const short8v bv = ld_bf8(pb + kt*32 + g*8);
        o = __builtin_amdgcn_mfma_f32_16x16x32_bf16(av, bv, o, 0, 0, 0);
    }
    const float iv = invl[qt2*16 + c];
    const size_t oidx = (size_t)(b * S_ + q0 + qt2*16 + c) * D_ + h * HD_ + dt*16 + g*4;
    ushort4 hh, ll;
    {
        const float v0 = o[0]*iv, v1 = o[1]*iv, v2 = o[2]*iv, v3 = o[3]*iv;
        hh.x = f2bf(v0); ll.x = f2bf(v0 - bf2f(hh.x));
        hh.y = f2bf(v1); ll.y = f2bf(v1 - bf2f(hh.y));
        hh.z = f2bf(v2); ll.z = f2bf(v2 - bf2f(hh.z));
        hh.w = f2bf(v3); ll.w = f2bf(v3 - bf2f(hh.w));
    }
    *(ushort4*)(aoh + oidx) = hh;
    *(ushort4*)(aol + oidx) = ll;
}

extern "C" void kernel_launch(void* const* d_in, const int* in_sizes, int n_in,
                              void* d_out, int out_size, void* d_ws, size_t ws_size,
                              hipStream_t stream)
{
    const float* x     = (const float*)d_in[0];
    const float* w_in  = (const float*)d_in[1];
    const float* b_in  = (const float*)d_in[2];
    const float* w_out = (const float*)d_in[3];
    const float* b_out = (const float*)d_in[4];
    const float* gw1   = (const float*)d_in[5];
    const float* gb1   = (const float*)d_in[6];
    const float* gw2   = (const float*)d_in[7];
    // d_in[8] = gate_b2: constant inside monotone sigmoid -> doesn't affect top-k

    float* ws = (float*)d_ws;
    int* meta = (int*)(ws + OFF_META);
    int* kidx = (int*)(ws + OFF_KIDX);
    unsigned short* KG  = (unsigned short*)(ws + OFF_KG);
    unsigned short* VTg = (unsigned short*)(ws + OFF_VT);
    unsigned short* Qb  = (unsigned short*)(ws + OFF_Q);
    unsigned short* XH  = (unsigned short*)(ws + OFF_XH);
    unsigned short* XL  = (unsigned short*)(ws + OFF_XL);
    unsigned short* AOH = (unsigned short*)(ws + OFF_AOH);
    unsigned short* AOL = (unsigned short*)(ws + OFF_AOL);
    unsigned short* WIH = (unsigned short*)(ws + OFF_WIH);
    unsigned short* WIL = (unsigned short*)(ws + OFF_WIL);
    unsigned short* WOH = (unsigned short*)(ws + OFF_WOH);
    unsigned short* WOL = (unsigned short*)(ws + OFF_WOL);
    float* out = (float*)d_out;

    // gate + plane conversion (x, w_in, w_out) + meta zero
    gate_kernel<<<B_ * S_ / 8, 256, 0, stream>>>(x, gw1, gb1, gw2, w_in, w_out, ws);
    // exact-rank top-k with ticketed emit
    rank_kernel<<<B_ * 128, 256, 0, stream>>>(ws + OFF_IMP, kidx, meta);
    // fused Q projection + gathered K/V projection (V written pre-transposed)
    proj_kernel<<<dim3(160, 4), 256, 0, stream>>>(
        XH, XL, WIH, WIL, b_in, Qb, KG, VTg, kidx);
    // attention
    attn_kernel<<<dim3(S_ / 32, H_, B_), 256, 0, stream>>>(KG, VTg, Qb, AOH, AOL);
    // out = AO @ w_out^T + b_out  (fp32 output)
    gemm_kernel<<<dim3(B_ * S_ / 64, D_ / 64), 256, 0, stream>>>(
        AOH, AOL, WOH, WOL, b_out, out);
}